// Round 1
// baseline (670.747 us; speedup 1.0000x reference)
//
#include <hip/hip_runtime.h>
#include <stdint.h>

#define B_ 16
#define S_ 64
#define M_ 4096
#define D_ 1024
#define H_ 16
#define DH_ 64

typedef unsigned short ushort_t;
typedef __attribute__((ext_vector_type(8))) __bf16 bfrag;   // 8 bf16 = 4 VGPRs (matches V8y builtin sig)
typedef __attribute__((ext_vector_type(4))) float f32x4;

// fp32 -> bf16 RNE
__device__ __forceinline__ ushort_t f2bf(float f) {
  union { float f; uint32_t u; } v; v.f = f;
  uint32_t r = v.u + 0x7fffu + ((v.u >> 16) & 1u);
  return (ushort_t)(r >> 16);
}

// async global->LDS, 16B per lane; LDS dst is wave-uniform base + lane*16
__device__ __forceinline__ void gload_lds16(const void* g, void* l) {
  __builtin_amdgcn_global_load_lds((const __attribute__((address_space(1))) void*)g,
                                   (__attribute__((address_space(3))) void*)l, 16, 0, 0);
}

__device__ __forceinline__ f32x4 mfma16x16x32(bfrag a, bfrag b, f32x4 c) {
  return __builtin_amdgcn_mfma_f32_16x16x32_bf16(a, b, c, 0, 0, 0);
}

// ---------------- LayerNorm rows (1024 wide) -> bf16 ----------------
__global__ __launch_bounds__(256) void ln_rows_kernel(
    const float* __restrict__ x, const float* __restrict__ g,
    const float* __restrict__ bta, ushort_t* __restrict__ out) {
  const int row = blockIdx.x;
  const int t = threadIdx.x;
  const float4* xr = (const float4*)(x + (size_t)row * D_);
  float4 v = xr[t];
  float s = v.x + v.y + v.z + v.w;
  float ss = v.x * v.x + v.y * v.y + v.z * v.z + v.w * v.w;
#pragma unroll
  for (int o = 32; o >= 1; o >>= 1) { s += __shfl_down(s, o); ss += __shfl_down(ss, o); }
  __shared__ float red[16];
  const int wid = t >> 6;
  if ((t & 63) == 0) { red[wid] = s; red[8 + wid] = ss; }
  __syncthreads();
  float tot = red[0] + red[1] + red[2] + red[3];
  float tot2 = red[8] + red[9] + red[10] + red[11];
  float mu = tot * (1.0f / D_);
  float var = tot2 * (1.0f / D_) - mu * mu;
  float rstd = rsqrtf(var + 1e-5f);
  float4 gg = ((const float4*)g)[t];
  float4 bb = ((const float4*)bta)[t];
  ushort_t ob[4];
  ob[0] = f2bf((v.x - mu) * rstd * gg.x + bb.x);
  ob[1] = f2bf((v.y - mu) * rstd * gg.y + bb.y);
  ob[2] = f2bf((v.z - mu) * rstd * gg.z + bb.z);
  ob[3] = f2bf((v.w - mu) * rstd * gg.w + bb.w);
  *(uint2*)(out + (size_t)row * D_ + t * 4) = *(const uint2*)ob;
}

// ---------------- W[K=1024][N] fp32 -> WT[N][1024] bf16 (scaled) ----------------
__global__ void transpose_cast_kernel(const float* __restrict__ W, ushort_t* __restrict__ WT,
                                      int N, float scale) {
  __shared__ float tile[32][33];
  const int n0 = blockIdx.x * 32, k0 = blockIdx.y * 32;
  const int tx = threadIdx.x, ty = threadIdx.y;
#pragma unroll
  for (int i = ty; i < 32; i += 8)
    tile[i][tx] = W[(size_t)(k0 + i) * N + n0 + tx];
  __syncthreads();
#pragma unroll
  for (int i = ty; i < 32; i += 8)
    WT[(size_t)(n0 + i) * D_ + k0 + tx] = f2bf(tile[tx][i] * scale);
}

// ---------------- generic 128x128 GEMM, C = A * Bt^T (both row-major [rows][K]) ----
// MODE 0: C0 = fp32 out, ldc = 1024   (final projection)
// MODE 1: scatter bf16 to k/v buffers (b,h,s,d)
template <int MODE>
__global__ __launch_bounds__(256) void gemm_bt_kernel(
    const ushort_t* __restrict__ A, const ushort_t* __restrict__ Bt,
    void* __restrict__ C0, void* __restrict__ C1, int K) {
  __shared__ __align__(16) ushort_t sA[128 * 32];
  __shared__ __align__(16) ushort_t sB[128 * 32];
  const int tid = threadIdx.x, wid = tid >> 6, lane = tid & 63;
  const size_t arow0 = (size_t)blockIdx.x * 128;
  const size_t brow0 = (size_t)blockIdx.y * 128;
  const int wr = (wid >> 1) * 64, wc = (wid & 1) * 64;
  const int srow = tid >> 2, scol = (tid & 3) * 8;
  const ushort_t* ga = A + (arow0 + srow) * (size_t)K + scol;
  const ushort_t* gb = Bt + (brow0 + srow) * (size_t)K + scol;
  const int frow = lane & 15, kslot = (lane >> 4) * 8;
  f32x4 acc[4][4] = {};
  for (int k0 = 0; k0 < K; k0 += 32) {
    gload_lds16(ga, sA + wid * 512);
    gload_lds16(ga + 64 * (size_t)K, sA + 2048 + wid * 512);
    gload_lds16(gb, sB + wid * 512);
    gload_lds16(gb + 64 * (size_t)K, sB + 2048 + wid * 512);
    ga += 32; gb += 32;
    __syncthreads();
    bfrag af[4], bfv[4];
#pragma unroll
    for (int m = 0; m < 4; ++m)
      af[m] = *(const bfrag*)&sA[(wr + m * 16 + frow) * 32 + kslot];
#pragma unroll
    for (int n = 0; n < 4; ++n)
      bfv[n] = *(const bfrag*)&sB[(wc + n * 16 + frow) * 32 + kslot];
#pragma unroll
    for (int m = 0; m < 4; ++m)
#pragma unroll
      for (int n = 0; n < 4; ++n)
        acc[m][n] = mfma16x16x32(af[m], bfv[n], acc[m][n]);
    __syncthreads();
  }
  const int erow = (lane >> 4) * 4, ecol = lane & 15;
  if constexpr (MODE == 0) {
    float* C = (float*)C0;
#pragma unroll
    for (int m = 0; m < 4; ++m)
#pragma unroll
      for (int n = 0; n < 4; ++n)
#pragma unroll
        for (int r = 0; r < 4; ++r)
          C[(arow0 + wr + m * 16 + erow + r) * 1024 + brow0 + wc + n * 16 + ecol] =
              acc[m][n][r];
  } else {
    ushort_t* kb = (ushort_t*)C0;
    ushort_t* vb = (ushort_t*)C1;
#pragma unroll
    for (int m = 0; m < 4; ++m)
#pragma unroll
      for (int n = 0; n < 4; ++n)
#pragma unroll
        for (int r = 0; r < 4; ++r) {
          size_t i = arow0 + wr + m * 16 + erow + r;
          int bb = (int)(i >> 6), s = (int)(i & 63);
          size_t n2 = brow0 + wc + n * 16 + ecol;
          ushort_t val = f2bf(acc[m][n][r]);
          ushort_t* dst = (n2 < 1024) ? kb : vb;
          size_t hh = (n2 & 1023) >> 6, d = n2 & 63;
          dst[(((size_t)bb * H_ + hh) * S_ + s) * DH_ + d] = val;
        }
  }
}

// ---------------- fused q-proj + attention per (b, h, 128-row m-tile) -------------
// q = lnl_tile @ WqT(h)^T (scale folded into WqT); sim = q k^T; softmax over 64;
// out1[i][j] = sum_s attn[i][s] * v[j][s]  (source einsum quirk: v row-major [S][DH])
__global__ __launch_bounds__(256) void qattn_kernel(
    const ushort_t* __restrict__ lnl, const ushort_t* __restrict__ wqT,
    const ushort_t* __restrict__ kbuf, const ushort_t* __restrict__ vbuf,
    ushort_t* __restrict__ out1) {
  __shared__ __align__(16) ushort_t sA[128 * 32];
  __shared__ __align__(16) ushort_t sW[64 * 32];
  __shared__ __align__(16) ushort_t sK[64 * 64];
  __shared__ __align__(16) ushort_t sV[64 * 64];
  __shared__ __align__(16) ushort_t sP[128 * 64];
  const int tid = threadIdx.x, wid = tid >> 6, lane = tid & 63;
  const int mt = blockIdx.x, h = blockIdx.y, b = blockIdx.z;
  const size_t arow0 = (size_t)b * M_ + (size_t)mt * 128;

  const ushort_t* kg = kbuf + ((size_t)b * H_ + h) * (S_ * DH_);
  const ushort_t* vg = vbuf + ((size_t)b * H_ + h) * (S_ * DH_);
  // stage K,V (8KB each = 2 passes of 256thr*16B)
  gload_lds16(kg + (size_t)tid * 8, sK + wid * 512);
  gload_lds16(kg + 2048 + (size_t)tid * 8, sK + 2048 + wid * 512);
  gload_lds16(vg + (size_t)tid * 8, sV + wid * 512);
  gload_lds16(vg + 2048 + (size_t)tid * 8, sV + 2048 + wid * 512);

  const int srow = tid >> 2, scol = (tid & 3) * 8;
  const ushort_t* ga = lnl + (arow0 + srow) * D_ + scol;
  const ushort_t* gw = wqT + ((size_t)h * 64 + srow) * D_ + scol;
  const int frow = lane & 15, kslot = (lane >> 4) * 8;
  const int wrow = wid * 32;  // wave owns rows [wrow, wrow+32)

  // Phase 1: q tile (128x64), K=1024
  f32x4 accq[2][4] = {};
  for (int k0 = 0; k0 < D_; k0 += 32) {
    gload_lds16(ga, sA + wid * 512);
    gload_lds16(ga + 64 * D_, sA + 2048 + wid * 512);
    gload_lds16(gw, sW + wid * 512);
    ga += 32; gw += 32;
    __syncthreads();
    bfrag af[2], wf[4];
#pragma unroll
    for (int m = 0; m < 2; ++m)
      af[m] = *(const bfrag*)&sA[(wrow + m * 16 + frow) * 32 + kslot];
#pragma unroll
    for (int n = 0; n < 4; ++n)
      wf[n] = *(const bfrag*)&sW[(n * 16 + frow) * 32 + kslot];
#pragma unroll
    for (int m = 0; m < 2; ++m)
#pragma unroll
      for (int n = 0; n < 4; ++n)
        accq[m][n] = mfma16x16x32(af[m], wf[n], accq[m][n]);
    __syncthreads();
  }

  const int erow = (lane >> 4) * 4, ecol = lane & 15;
  // q -> sP bf16
#pragma unroll
  for (int m = 0; m < 2; ++m)
#pragma unroll
    for (int n = 0; n < 4; ++n)
#pragma unroll
      for (int r = 0; r < 4; ++r)
        sP[(wrow + m * 16 + erow + r) * 64 + n * 16 + ecol] = f2bf(accq[m][n][r]);
  __syncthreads();

  // Phase 2: sim = q @ k^T (K = DH = 64)
  f32x4 accs[2][4] = {};
#pragma unroll
  for (int kk = 0; kk < 2; ++kk) {
    bfrag qf[2], kf[4];
#pragma unroll
    for (int m = 0; m < 2; ++m)
      qf[m] = *(const bfrag*)&sP[(wrow + m * 16 + frow) * 64 + kk * 32 + kslot];
#pragma unroll
    for (int n = 0; n < 4; ++n)
      kf[n] = *(const bfrag*)&sK[(n * 16 + frow) * 64 + kk * 32 + kslot];
#pragma unroll
    for (int m = 0; m < 2; ++m)
#pragma unroll
      for (int n = 0; n < 4; ++n)
        accs[m][n] = mfma16x16x32(qf[m], kf[n], accs[m][n]);
  }

  // Phase 3: softmax over 64 cols; row lives in one 16-lane group, 4 cols/lane
#pragma unroll
  for (int m = 0; m < 2; ++m) {
#pragma unroll
    for (int r = 0; r < 4; ++r) {
      float mx = fmaxf(fmaxf(accs[m][0][r], accs[m][1][r]),
                       fmaxf(accs[m][2][r], accs[m][3][r]));
#pragma unroll
      for (int o = 1; o < 16; o <<= 1) mx = fmaxf(mx, __shfl_xor(mx, o));
      float e0 = __expf(accs[m][0][r] - mx);
      float e1 = __expf(accs[m][1][r] - mx);
      float e2 = __expf(accs[m][2][r] - mx);
      float e3 = __expf(accs[m][3][r] - mx);
      float sm = e0 + e1 + e2 + e3;
#pragma unroll
      for (int o = 1; o < 16; o <<= 1) sm += __shfl_xor(sm, o);
      float inv = 1.0f / sm;
      accs[m][0][r] = e0 * inv; accs[m][1][r] = e1 * inv;
      accs[m][2][r] = e2 * inv; accs[m][3][r] = e3 * inv;
    }
  }
  __syncthreads();
  // attn -> sP (wave-private rows)
#pragma unroll
  for (int m = 0; m < 2; ++m)
#pragma unroll
    for (int n = 0; n < 4; ++n)
#pragma unroll
      for (int r = 0; r < 4; ++r)
        sP[(wrow + m * 16 + erow + r) * 64 + n * 16 + ecol] = f2bf(accs[m][n][r]);
  __syncthreads();

  // Phase 4: out1 = attn @ v^T  (contraction over attn's key axis vs v's feature axis)
  f32x4 acco[2][4] = {};
#pragma unroll
  for (int kk = 0; kk < 2; ++kk) {
    bfrag pf[2], vf[4];
#pragma unroll
    for (int m = 0; m < 2; ++m)
      pf[m] = *(const bfrag*)&sP[(wrow + m * 16 + frow) * 64 + kk * 32 + kslot];
#pragma unroll
    for (int n = 0; n < 4; ++n)
      vf[n] = *(const bfrag*)&sV[(n * 16 + frow) * 64 + kk * 32 + kslot];
#pragma unroll
    for (int m = 0; m < 2; ++m)
#pragma unroll
      for (int n = 0; n < 4; ++n)
        acco[m][n] = mfma16x16x32(pf[m], vf[n], acco[m][n]);
  }
  __syncthreads();
  // out1 -> sP bf16
#pragma unroll
  for (int m = 0; m < 2; ++m)
#pragma unroll
    for (int n = 0; n < 4; ++n)
#pragma unroll
      for (int r = 0; r < 4; ++r)
        sP[(wrow + m * 16 + erow + r) * 64 + n * 16 + ecol] = f2bf(acco[m][n][r]);
  __syncthreads();

  // coalesced tile store: rows -> out1[(b*M+row)][h*64 + d]
#pragma unroll
  for (int p = 0; p < 4; ++p) {
    int row = p * 32 + (tid >> 3);
    int ce = (tid & 7) * 8;
    *(uint4*)&out1[(arow0 + row) * 1024 + h * 64 + ce] = *(const uint4*)&sP[row * 64 + ce];
  }
}

// -------------------------------- launch --------------------------------
extern "C" void kernel_launch(void* const* d_in, const int* in_sizes, int n_in,
                              void* d_out, int out_size, void* d_ws, size_t ws_size,
                              hipStream_t stream) {
  const float* x = (const float*)d_in[0];
  const float* lat = (const float*)d_in[1];
  const float* lxg = (const float*)d_in[2];
  const float* lxb = (const float*)d_in[3];
  const float* llg = (const float*)d_in[4];
  const float* llb = (const float*)d_in[5];
  const float* Wq = (const float*)d_in[6];
  const float* Wkv = (const float*)d_in[7];
  const float* Wout = (const float*)d_in[8];
  float* out = (float*)d_out;
  char* ws = (char*)d_ws;

  // ws layout (142MB): xn 2MB | wqT 2MB | wkvT 4MB | woT 2MB | k 2MB | v 2MB | out1 128MB
  ushort_t* xn = (ushort_t*)(ws);
  ushort_t* wqT = (ushort_t*)(ws + (2ull << 20));
  ushort_t* wkvT = (ushort_t*)(ws + (4ull << 20));
  ushort_t* woT = (ushort_t*)(ws + (8ull << 20));
  ushort_t* kbuf = (ushort_t*)(ws + (10ull << 20));
  ushort_t* vbuf = (ushort_t*)(ws + (12ull << 20));
  ushort_t* out1 = (ushort_t*)(ws + (14ull << 20));
  // lnl (bf16, 128MB) lives in d_out's first half: dead before final GEMM overwrites d_out
  ushort_t* lnl = (ushort_t*)d_out;

  dim3 tb(32, 8);
  transpose_cast_kernel<<<dim3(1024 / 32, 32), tb, 0, stream>>>(Wq, wqT, 1024, 0.125f);
  transpose_cast_kernel<<<dim3(2048 / 32, 32), tb, 0, stream>>>(Wkv, wkvT, 2048, 1.0f);
  transpose_cast_kernel<<<dim3(1024 / 32, 32), tb, 0, stream>>>(Wout, woT, 1024, 1.0f);
  ln_rows_kernel<<<B_ * S_, 256, 0, stream>>>(x, lxg, lxb, xn);
  ln_rows_kernel<<<B_ * M_, 256, 0, stream>>>(lat, llg, llb, lnl);
  gemm_bt_kernel<1><<<dim3(8, 16), 256, 0, stream>>>(xn, wkvT, kbuf, vbuf, 1024);
  qattn_kernel<<<dim3(32, 16, 16), 256, 0, stream>>>(lnl, wqT, kbuf, vbuf, out1);
  gemm_bt_kernel<0><<<dim3(512, 8), 256, 0, stream>>>(out1, woT, out, nullptr, 1024);
}

// Round 2
// 616.278 us; speedup vs baseline: 1.0884x; 1.0884x over previous
//
#include <hip/hip_runtime.h>
#include <stdint.h>

#define B_ 16
#define S_ 64
#define M_ 4096
#define D_ 1024
#define H_ 16
#define DH_ 64

typedef unsigned short ushort_t;
typedef __attribute__((ext_vector_type(8))) __bf16 bfrag;   // 8 bf16 = 4 VGPRs
typedef __attribute__((ext_vector_type(4))) float f32x4;

// fp32 -> bf16 RNE
__device__ __forceinline__ ushort_t f2bf(float f) {
  union { float f; uint32_t u; } v; v.f = f;
  uint32_t r = v.u + 0x7fffu + ((v.u >> 16) & 1u);
  return (ushort_t)(r >> 16);
}

// async global->LDS, 16B per lane; LDS dst is wave-uniform base + lane*16
__device__ __forceinline__ void gload_lds16(const void* g, void* l) {
  __builtin_amdgcn_global_load_lds((const __attribute__((address_space(1))) void*)g,
                                   (__attribute__((address_space(3))) void*)l, 16, 0, 0);
}

__device__ __forceinline__ f32x4 mfma16x16x32(bfrag a, bfrag b, f32x4 c) {
  return __builtin_amdgcn_mfma_f32_16x16x32_bf16(a, b, c, 0, 0, 0);
}

// ---------------- LayerNorm rows (1024 wide) -> bf16 ----------------
__global__ __launch_bounds__(256) void ln_rows_kernel(
    const float* __restrict__ x, const float* __restrict__ g,
    const float* __restrict__ bta, ushort_t* __restrict__ out) {
  const int row = blockIdx.x;
  const int t = threadIdx.x;
  const float4* xr = (const float4*)(x + (size_t)row * D_);
  float4 v = xr[t];
  float s = v.x + v.y + v.z + v.w;
  float ss = v.x * v.x + v.y * v.y + v.z * v.z + v.w * v.w;
#pragma unroll
  for (int o = 32; o >= 1; o >>= 1) { s += __shfl_down(s, o); ss += __shfl_down(ss, o); }
  __shared__ float red[16];
  const int wid = t >> 6;
  if ((t & 63) == 0) { red[wid] = s; red[8 + wid] = ss; }
  __syncthreads();
  float tot = red[0] + red[1] + red[2] + red[3];
  float tot2 = red[8] + red[9] + red[10] + red[11];
  float mu = tot * (1.0f / D_);
  float var = tot2 * (1.0f / D_) - mu * mu;
  float rstd = rsqrtf(var + 1e-5f);
  float4 gg = ((const float4*)g)[t];
  float4 bb = ((const float4*)bta)[t];
  ushort_t ob[4];
  ob[0] = f2bf((v.x - mu) * rstd * gg.x + bb.x);
  ob[1] = f2bf((v.y - mu) * rstd * gg.y + bb.y);
  ob[2] = f2bf((v.z - mu) * rstd * gg.z + bb.z);
  ob[3] = f2bf((v.w - mu) * rstd * gg.w + bb.w);
  *(uint2*)(out + (size_t)row * D_ + t * 4) = *(const uint2*)ob;
}

// ---------------- W[K=1024][N] fp32 -> WT[N][1024] bf16 (scaled) ----------------
__global__ void transpose_cast_kernel(const float* __restrict__ W, ushort_t* __restrict__ WT,
                                      int N, float scale) {
  __shared__ float tile[32][33];
  const int n0 = blockIdx.x * 32, k0 = blockIdx.y * 32;
  const int tx = threadIdx.x, ty = threadIdx.y;
#pragma unroll
  for (int i = ty; i < 32; i += 8)
    tile[i][tx] = W[(size_t)(k0 + i) * N + n0 + tx];
  __syncthreads();
#pragma unroll
  for (int i = ty; i < 32; i += 8)
    WT[(size_t)(n0 + i) * D_ + k0 + tx] = f2bf(tile[tx][i] * scale);
}

// ---------------- generic 128x128 GEMM, C = A * Bt^T (both row-major [rows][K]) ----
// MODE 0: C0 = fp32 out, ldc = 1024   (final projection)
// MODE 1: scatter bf16 to k/v buffers (b,h,s,d)
template <int MODE>
__global__ __launch_bounds__(256) void gemm_bt_kernel(
    const ushort_t* __restrict__ A, const ushort_t* __restrict__ Bt,
    void* __restrict__ C0, void* __restrict__ C1, int K) {
  __shared__ __align__(16) ushort_t sA[128 * 32];
  __shared__ __align__(16) ushort_t sB[128 * 32];
  const int tid = threadIdx.x, wid = tid >> 6, lane = tid & 63;
  const size_t arow0 = (size_t)blockIdx.x * 128;
  const size_t brow0 = (size_t)blockIdx.y * 128;
  const int wr = (wid >> 1) * 64, wc = (wid & 1) * 64;
  const int srow = tid >> 2, scol = (tid & 3) * 8;
  const ushort_t* ga = A + (arow0 + srow) * (size_t)K + scol;
  const ushort_t* gb = Bt + (brow0 + srow) * (size_t)K + scol;
  const int frow = lane & 15, kslot = (lane >> 4) * 8;
  f32x4 acc[4][4] = {};
  for (int k0 = 0; k0 < K; k0 += 32) {
    gload_lds16(ga, sA + wid * 512);
    gload_lds16(ga + 64 * (size_t)K, sA + 2048 + wid * 512);
    gload_lds16(gb, sB + wid * 512);
    gload_lds16(gb + 64 * (size_t)K, sB + 2048 + wid * 512);
    ga += 32; gb += 32;
    __syncthreads();
    bfrag af[4], bfv[4];
#pragma unroll
    for (int m = 0; m < 4; ++m)
      af[m] = *(const bfrag*)&sA[(wr + m * 16 + frow) * 32 + kslot];
#pragma unroll
    for (int n = 0; n < 4; ++n)
      bfv[n] = *(const bfrag*)&sB[(wc + n * 16 + frow) * 32 + kslot];
#pragma unroll
    for (int m = 0; m < 4; ++m)
#pragma unroll
      for (int n = 0; n < 4; ++n)
        acc[m][n] = mfma16x16x32(af[m], bfv[n], acc[m][n]);
    __syncthreads();
  }
  const int erow = (lane >> 4) * 4, ecol = lane & 15;
  if constexpr (MODE == 0) {
    float* C = (float*)C0;
#pragma unroll
    for (int m = 0; m < 4; ++m)
#pragma unroll
      for (int n = 0; n < 4; ++n)
#pragma unroll
        for (int r = 0; r < 4; ++r)
          C[(arow0 + wr + m * 16 + erow + r) * 1024 + brow0 + wc + n * 16 + ecol] =
              acc[m][n][r];
  } else {
    ushort_t* kb = (ushort_t*)C0;
    ushort_t* vb = (ushort_t*)C1;
#pragma unroll
    for (int m = 0; m < 4; ++m)
#pragma unroll
      for (int n = 0; n < 4; ++n)
#pragma unroll
        for (int r = 0; r < 4; ++r) {
          size_t i = arow0 + wr + m * 16 + erow + r;
          int bb = (int)(i >> 6), s = (int)(i & 63);
          size_t n2 = brow0 + wc + n * 16 + ecol;
          ushort_t val = f2bf(acc[m][n][r]);
          ushort_t* dst = (n2 < 1024) ? kb : vb;
          size_t hh = (n2 & 1023) >> 6, d = n2 & 63;
          dst[(((size_t)bb * H_ + hh) * S_ + s) * DH_ + d] = val;
        }
  }
}

// ---------------- fused q-proj + attention, 128 rows x 2 heads per block ----------
// Tile: q[128][128] (2 heads), 4 waves 2x2 (wr in {0,64}, wc in {0,64}).
// Each wave's 64x64 quadrant = one head x 64 rows -> attention epilogue is
// wave-private (no barriers between q-write / sim / softmax / PV / out-write).
// All LDS accesses XOR-swizzled: gload_lds buffers via pre-swizzled global
// source (dest linear), VALU-written sQP via granule ^= row&15 on both sides.
__global__ __launch_bounds__(256) void qattn_kernel(
    const ushort_t* __restrict__ lnl, const ushort_t* __restrict__ wqT,
    const ushort_t* __restrict__ kbuf, const ushort_t* __restrict__ vbuf,
    ushort_t* __restrict__ out1) {
  __shared__ __align__(16) ushort_t sKV[4 * 4096];  // K0 V0 K1 V1, 8KB each, swz rows%8
  __shared__ __align__(16) ushort_t sU[16384];      // 32KB union: {sA,sW} then sQP[128][128]
  ushort_t* const sA = sU;                          // [128][64]
  ushort_t* const sW = sU + 8192;                   // [128][64]
  ushort_t* const sQP = sU;                         // [128][128]

  const int tid = threadIdx.x, wid = tid >> 6, lane = tid & 63;
  const int mt = blockIdx.x, hp = blockIdx.y, b = blockIdx.z;
  const size_t arow0 = (size_t)b * M_ + (size_t)mt * 128;
  const int wr = (wid >> 1) * 64, wc = (wid & 1) * 64;
  const int frow = lane & 15;       // fragment row/col within 16
  const int klo = lane >> 4;        // k-granule base 0..3

  // ---- phase 0: stage K,V for heads (2hp, 2hp+1); source pre-swizzled g^=row&7
  {
    const size_t bh0 = ((size_t)b * H_ + (size_t)hp * 2) * (size_t)(S_ * DH_);
    const int row = tid >> 3;
    const size_t off = (size_t)row * 64 + (size_t)(((tid & 7) ^ (row & 7)) * 8);
    const ushort_t* k0 = kbuf + bh0;
    const ushort_t* v0 = vbuf + bh0;
    ushort_t* dst = sKV + wid * 512;
    gload_lds16(k0 + off, dst);
    gload_lds16(k0 + off + 2048, dst + 2048);
    gload_lds16(v0 + off, dst + 4096);
    gload_lds16(v0 + off + 2048, dst + 6144);
    gload_lds16(k0 + off + 4096, dst + 8192);
    gload_lds16(k0 + off + 6144, dst + 10240);
    gload_lds16(v0 + off + 4096, dst + 12288);
    gload_lds16(v0 + off + 6144, dst + 14336);
  }

  // ---- phase 1: q[128][128] = lnl_tile @ wqT_rows^T, K=1024, BK=64
  const int srow = tid >> 3;                          // staging row 0..31
  const int sg8 = ((tid & 7) ^ (srow & 7)) * 8;       // pre-swizzled source granule
  const ushort_t* ga = lnl + (arow0 + srow) * (size_t)D_ + sg8;
  const ushort_t* gw = wqT + ((size_t)hp * 128 + srow) * (size_t)D_ + sg8;
  const int ra8 = (klo ^ (frow & 7)) << 3;            // swz elem off (kk=0); kk=1 -> ^32

  f32x4 acc[4][4] = {};
  for (int kI = 0; kI < D_; kI += 64) {
#pragma unroll
    for (int s = 0; s < 4; ++s) {
      gload_lds16(ga + (size_t)(s * 32) * D_, sA + s * 2048 + wid * 512);
      gload_lds16(gw + (size_t)(s * 32) * D_, sW + s * 2048 + wid * 512);
    }
    ga += 64; gw += 64;
    __syncthreads();
    bfrag af[4][2], wf[4][2];
#pragma unroll
    for (int m = 0; m < 4; ++m) {
      const int rb = (wr + m * 16 + frow) * 64;
      af[m][0] = *(const bfrag*)&sA[rb + ra8];
      af[m][1] = *(const bfrag*)&sA[rb + (ra8 ^ 32)];
    }
#pragma unroll
    for (int n = 0; n < 4; ++n) {
      const int rb = (wc + n * 16 + frow) * 64;
      wf[n][0] = *(const bfrag*)&sW[rb + ra8];
      wf[n][1] = *(const bfrag*)&sW[rb + (ra8 ^ 32)];
    }
#pragma unroll
    for (int kk = 0; kk < 2; ++kk)
#pragma unroll
      for (int m = 0; m < 4; ++m)
#pragma unroll
        for (int n = 0; n < 4; ++n)
          acc[m][n] = mfma16x16x32(af[m][kk], wf[n][kk], acc[m][n]);
    __syncthreads();
  }

  // ---- phase 2: q -> sQP bf16, granule ^= row&15 (quadrant-private)
  const int erow = klo * 4;   // C-frag: row=(lane>>4)*4+r, col=lane&15
#pragma unroll
  for (int m = 0; m < 4; ++m)
#pragma unroll
    for (int r = 0; r < 4; ++r) {
      const int rx = erow + r;                        // row & 15
      ushort_t* dst = &sQP[(wr + m * 16 + rx) * 128];
#pragma unroll
      for (int n = 0; n < 4; ++n) {
        const int col = wc + n * 16 + frow;
        dst[(((col >> 3) ^ rx) << 3) | (frow & 7)] = f2bf(acc[m][n][r]);
      }
    }

  // ---- phase 3: sim = q @ K^T (head = wc/64), K-dim = DH = 64
  const ushort_t* const sKh = sKV + (wc >> 6) * 8192;
  const ushort_t* const sVh = sKh + 4096;
  const int q8 = ((((wc >> 3) + klo) ^ frow) << 3);   // swz elem off in sQP (kk=0)
  f32x4 accs[4][4] = {};
#pragma unroll
  for (int kk = 0; kk < 2; ++kk) {
    bfrag qf[4], kf[4];
#pragma unroll
    for (int m = 0; m < 4; ++m)
      qf[m] = *(const bfrag*)&sQP[(wr + m * 16 + frow) * 128 + (kk ? (q8 ^ 32) : q8)];
#pragma unroll
    for (int n = 0; n < 4; ++n)
      kf[n] = *(const bfrag*)&sKh[(n * 16 + frow) * 64 + (kk ? (ra8 ^ 32) : ra8)];
#pragma unroll
    for (int m = 0; m < 4; ++m)
#pragma unroll
      for (int n = 0; n < 4; ++n)
        accs[m][n] = mfma16x16x32(qf[m], kf[n], accs[m][n]);
  }

  // ---- phase 4: softmax over 64 keys; row = 16 lanes x 4 regs
#pragma unroll
  for (int m = 0; m < 4; ++m)
#pragma unroll
    for (int r = 0; r < 4; ++r) {
      float a0 = accs[m][0][r], a1 = accs[m][1][r], a2 = accs[m][2][r], a3 = accs[m][3][r];
      float mx = fmaxf(fmaxf(a0, a1), fmaxf(a2, a3));
#pragma unroll
      for (int o = 1; o < 16; o <<= 1) mx = fmaxf(mx, __shfl_xor(mx, o));
      a0 = __expf(a0 - mx); a1 = __expf(a1 - mx);
      a2 = __expf(a2 - mx); a3 = __expf(a3 - mx);
      float sm = (a0 + a1) + (a2 + a3);
#pragma unroll
      for (int o = 1; o < 16; o <<= 1) sm += __shfl_xor(sm, o);
      const float inv = 1.0f / sm;
      accs[m][0][r] = a0 * inv; accs[m][1][r] = a1 * inv;
      accs[m][2][r] = a2 * inv; accs[m][3][r] = a3 * inv;
    }

  // ---- phase 5: attn -> sQP (overwrite own q quadrant; wave-private)
#pragma unroll
  for (int m = 0; m < 4; ++m)
#pragma unroll
    for (int r = 0; r < 4; ++r) {
      const int rx = erow + r;
      ushort_t* dst = &sQP[(wr + m * 16 + rx) * 128];
#pragma unroll
      for (int n = 0; n < 4; ++n) {
        const int col = wc + n * 16 + frow;
        dst[(((col >> 3) ^ rx) << 3) | (frow & 7)] = f2bf(accs[m][n][r]);
      }
    }

  // ---- phase 6: out1 = attn @ V^T  (source einsum quirk: Bt rows = V rows as stored)
  f32x4 acco[4][4] = {};
#pragma unroll
  for (int kk = 0; kk < 2; ++kk) {
    bfrag pf[4], vf[4];
#pragma unroll
    for (int m = 0; m < 4; ++m)
      pf[m] = *(const bfrag*)&sQP[(wr + m * 16 + frow) * 128 + (kk ? (q8 ^ 32) : q8)];
#pragma unroll
    for (int n = 0; n < 4; ++n)
      vf[n] = *(const bfrag*)&sVh[(n * 16 + frow) * 64 + (kk ? (ra8 ^ 32) : ra8)];
#pragma unroll
    for (int m = 0; m < 4; ++m)
#pragma unroll
      for (int n = 0; n < 4; ++n)
        acco[m][n] = mfma16x16x32(pf[m], vf[n], acco[m][n]);
  }

  // ---- phase 7: out -> sQP (wave-private), then coalesced global store
#pragma unroll
  for (int m = 0; m < 4; ++m)
#pragma unroll
    for (int r = 0; r < 4; ++r) {
      const int rx = erow + r;
      ushort_t* dst = &sQP[(wr + m * 16 + rx) * 128];
#pragma unroll
      for (int n = 0; n < 4; ++n) {
        const int col = wc + n * 16 + frow;
        dst[(((col >> 3) ^ rx) << 3) | (frow & 7)] = f2bf(acco[m][n][r]);
      }
    }
  __syncthreads();
#pragma unroll
  for (int p = 0; p < 8; ++p) {
    const int row = p * 16 + (tid >> 4);
    const int gc = tid & 15;
    *(uint4*)&out1[(arow0 + row) * 1024 + (size_t)hp * 128 + gc * 8] =
        *(const uint4*)&sQP[row * 128 + ((gc ^ (row & 15)) << 3)];
  }
}

// -------------------------------- launch --------------------------------
extern "C" void kernel_launch(void* const* d_in, const int* in_sizes, int n_in,
                              void* d_out, int out_size, void* d_ws, size_t ws_size,
                              hipStream_t stream) {
  const float* x = (const float*)d_in[0];
  const float* lat = (const float*)d_in[1];
  const float* lxg = (const float*)d_in[2];
  const float* lxb = (const float*)d_in[3];
  const float* llg = (const float*)d_in[4];
  const float* llb = (const float*)d_in[5];
  const float* Wq = (const float*)d_in[6];
  const float* Wkv = (const float*)d_in[7];
  const float* Wout = (const float*)d_in[8];
  float* out = (float*)d_out;
  char* ws = (char*)d_ws;

  // ws layout (142MB): xn 2MB | wqT 2MB | wkvT 4MB | woT 2MB | k 2MB | v 2MB | out1 128MB
  ushort_t* xn = (ushort_t*)(ws);
  ushort_t* wqT = (ushort_t*)(ws + (2ull << 20));
  ushort_t* wkvT = (ushort_t*)(ws + (4ull << 20));
  ushort_t* woT = (ushort_t*)(ws + (8ull << 20));
  ushort_t* kbuf = (ushort_t*)(ws + (10ull << 20));
  ushort_t* vbuf = (ushort_t*)(ws + (12ull << 20));
  ushort_t* out1 = (ushort_t*)(ws + (14ull << 20));
  // lnl (bf16, 128MB) lives in d_out's first half: dead before final GEMM overwrites d_out
  ushort_t* lnl = (ushort_t*)d_out;

  dim3 tb(32, 8);
  transpose_cast_kernel<<<dim3(1024 / 32, 32), tb, 0, stream>>>(Wq, wqT, 1024, 0.125f);
  transpose_cast_kernel<<<dim3(2048 / 32, 32), tb, 0, stream>>>(Wkv, wkvT, 2048, 1.0f);
  transpose_cast_kernel<<<dim3(1024 / 32, 32), tb, 0, stream>>>(Wout, woT, 1024, 1.0f);
  ln_rows_kernel<<<B_ * S_, 256, 0, stream>>>(x, lxg, lxb, xn);
  ln_rows_kernel<<<B_ * M_, 256, 0, stream>>>(lat, llg, llb, lnl);
  gemm_bt_kernel<1><<<dim3(8, 16), 256, 0, stream>>>(xn, wkvT, kbuf, vbuf, 1024);
  qattn_kernel<<<dim3(32, 8, 16), 256, 0, stream>>>(lnl, wqT, kbuf, vbuf, out1);
  gemm_bt_kernel<0><<<dim3(512, 8), 256, 0, stream>>>(out1, woT, out, nullptr, 1024);
}

// Round 3
// 485.228 us; speedup vs baseline: 1.3823x; 1.2701x over previous
//
#include <hip/hip_runtime.h>
#include <stdint.h>

#define B_ 16
#define S_ 64
#define M_ 4096
#define D_ 1024
#define H_ 16
#define DH_ 64

typedef unsigned short ushort_t;
typedef __attribute__((ext_vector_type(8))) __bf16 bfrag;   // 8 bf16 = 4 VGPRs
typedef __attribute__((ext_vector_type(4))) float f32x4;

// fp32 -> bf16 RNE
__device__ __forceinline__ ushort_t f2bf(float f) {
  union { float f; uint32_t u; } v; v.f = f;
  uint32_t r = v.u + 0x7fffu + ((v.u >> 16) & 1u);
  return (ushort_t)(r >> 16);
}

__device__ __forceinline__ void gload_lds16(const void* g, void* l) {
  __builtin_amdgcn_global_load_lds((const __attribute__((address_space(1))) void*)g,
                                   (__attribute__((address_space(3))) void*)l, 16, 0, 0);
}

__device__ __forceinline__ f32x4 mfma16x16x32(bfrag a, bfrag b, f32x4 c) {
  return __builtin_amdgcn_mfma_f32_16x16x32_bf16(a, b, c, 0, 0, 0);
}

// epilogue-region swizzle: granule ^= fsw(row); fsw>>1 injective over klo groups
__device__ __forceinline__ int fsw(int r) { return (((r >> 2) & 3) << 1) | (r & 1); }

// ---------------- LayerNorm rows (1024 wide) -> bf16 ----------------
__global__ __launch_bounds__(256) void ln_rows_kernel(
    const float* __restrict__ x, const float* __restrict__ g,
    const float* __restrict__ bta, ushort_t* __restrict__ out) {
  const int row = blockIdx.x;
  const int t = threadIdx.x;
  const float4* xr = (const float4*)(x + (size_t)row * D_);
  float4 v = xr[t];
  float s = v.x + v.y + v.z + v.w;
  float ss = v.x * v.x + v.y * v.y + v.z * v.z + v.w * v.w;
#pragma unroll
  for (int o = 32; o >= 1; o >>= 1) { s += __shfl_down(s, o); ss += __shfl_down(ss, o); }
  __shared__ float red[16];
  const int wid = t >> 6;
  if ((t & 63) == 0) { red[wid] = s; red[8 + wid] = ss; }
  __syncthreads();
  float tot = red[0] + red[1] + red[2] + red[3];
  float tot2 = red[8] + red[9] + red[10] + red[11];
  float mu = tot * (1.0f / D_);
  float var = tot2 * (1.0f / D_) - mu * mu;
  float rstd = rsqrtf(var + 1e-5f);
  float4 gg = ((const float4*)g)[t];
  float4 bb = ((const float4*)bta)[t];
  ushort_t ob[4];
  ob[0] = f2bf((v.x - mu) * rstd * gg.x + bb.x);
  ob[1] = f2bf((v.y - mu) * rstd * gg.y + bb.y);
  ob[2] = f2bf((v.z - mu) * rstd * gg.z + bb.z);
  ob[3] = f2bf((v.w - mu) * rstd * gg.w + bb.w);
  *(uint2*)(out + (size_t)row * D_ + t * 4) = *(const uint2*)ob;
}

// ---------------- W[K=1024][N] fp32 -> WT[N][1024] bf16 (scaled) ----------------
__global__ void transpose_cast_kernel(const float* __restrict__ W, ushort_t* __restrict__ WT,
                                      int N, float scale) {
  __shared__ float tile[32][33];
  const int n0 = blockIdx.x * 32, k0 = blockIdx.y * 32;
  const int tx = threadIdx.x, ty = threadIdx.y;
#pragma unroll
  for (int i = ty; i < 32; i += 8)
    tile[i][tx] = W[(size_t)(k0 + i) * N + n0 + tx];
  __syncthreads();
#pragma unroll
  for (int i = ty; i < 32; i += 8)
    WT[(size_t)(n0 + i) * D_ + k0 + tx] = f2bf(tile[tx][i] * scale);
}

// ---------------- kv GEMM (small, 4.3 GF): 128x128, scatter to (b,h,s,d) ----------
__global__ __launch_bounds__(256) void gemm_kv_kernel(
    const ushort_t* __restrict__ A, const ushort_t* __restrict__ Bt,
    ushort_t* __restrict__ kb, ushort_t* __restrict__ vb) {
  __shared__ __align__(16) ushort_t sA[128 * 32];
  __shared__ __align__(16) ushort_t sB[128 * 32];
  const int tid = threadIdx.x, wid = tid >> 6, lane = tid & 63;
  const size_t arow0 = (size_t)blockIdx.x * 128;
  const size_t brow0 = (size_t)blockIdx.y * 128;
  const int wr = (wid >> 1) * 64, wc = (wid & 1) * 64;
  const int srow = tid >> 2, scol = (tid & 3) * 8;
  const ushort_t* ga = A + (arow0 + srow) * (size_t)D_ + scol;
  const ushort_t* gb = Bt + (brow0 + srow) * (size_t)D_ + scol;
  const int frow = lane & 15, kslot = (lane >> 4) * 8;
  f32x4 acc[4][4] = {};
  for (int k0 = 0; k0 < D_; k0 += 32) {
    gload_lds16(ga, sA + wid * 512);
    gload_lds16(ga + 64 * (size_t)D_, sA + 2048 + wid * 512);
    gload_lds16(gb, sB + wid * 512);
    gload_lds16(gb + 64 * (size_t)D_, sB + 2048 + wid * 512);
    ga += 32; gb += 32;
    __syncthreads();
    bfrag af[4], bfv[4];
#pragma unroll
    for (int m = 0; m < 4; ++m)
      af[m] = *(const bfrag*)&sA[(wr + m * 16 + frow) * 32 + kslot];
#pragma unroll
    for (int n = 0; n < 4; ++n)
      bfv[n] = *(const bfrag*)&sB[(wc + n * 16 + frow) * 32 + kslot];
#pragma unroll
    for (int m = 0; m < 4; ++m)
#pragma unroll
      for (int n = 0; n < 4; ++n)
        acc[m][n] = mfma16x16x32(af[m], bfv[n], acc[m][n]);
    __syncthreads();
  }
  const int erow = (lane >> 4) * 4, ecol = lane & 15;
#pragma unroll
  for (int m = 0; m < 4; ++m)
#pragma unroll
    for (int n = 0; n < 4; ++n)
#pragma unroll
      for (int r = 0; r < 4; ++r) {
        size_t i = arow0 + wr + m * 16 + erow + r;
        int bb = (int)(i >> 6), s = (int)(i & 63);
        size_t n2 = brow0 + wc + n * 16 + ecol;
        ushort_t val = f2bf(acc[m][n][r]);
        ushort_t* dst = (n2 < 1024) ? kb : vb;
        size_t hh = (n2 & 1023) >> 6, d = n2 & 63;
        dst[(((size_t)bb * H_ + hh) * S_ + s) * DH_ + d] = val;
      }
}

// ============== 256x256 pipelined GEMM (BK=32, counted vmcnt), C = A * Bt^T =======
// 8 waves (2m x 4n), per-wave 128x64 output. LDS 64KB:
//   A: [2 dbuf][2 p2][64 pair-rows][64]  (pair-row i holds wm0-row / wm1-row halves)
//   B: [2 dbuf][2 p1][64 pair-rows][64]  (pair-row t holds wn{0,1} / wn{2,3} halves)
// Per tile: phase0 {stage B0',B1'; vmcnt(3); bar; read ar(A0)+br(all B); 16 MFMA}
//           phase1 {stage A0',A1'; vmcnt(4); bar; read ar(A1); 16 MFMA; bar}
// MODE 0: epilogue = fp32 C store (out-projection)
// MODE 1: epilogue = fused attention per wave-half (head = nblk*4+wn), bf16 out1
template <int MODE>
__global__ __launch_bounds__(512, 2) void gemm256_kernel(
    const ushort_t* __restrict__ A, const ushort_t* __restrict__ Bt,
    const ushort_t* __restrict__ kbuf, const ushort_t* __restrict__ vbuf,
    void* __restrict__ Cout) {
  __shared__ __align__(16) ushort_t lds[32768];  // 64KB
  const int tid = threadIdx.x, wid = tid >> 6, lane = tid & 63;
  const int frow = lane & 15, klo = lane >> 4;
  const int wm = wid >> 2, wn = wid & 3;

  // XCD-swizzled block mapping (1024 = 8*128, bijective)
  const int l = ((int)blockIdx.x & 7) * 128 + ((int)blockIdx.x >> 3);
  const int mblk = l >> 2, nblk = l & 3;
  const size_t arow0 = (size_t)mblk * 256;
  const size_t bcol0 = (size_t)nblk * 256;

  // ---- per-thread staging constants (slot u = tid) ----
  const int srow = tid >> 3;            // pair-row 0..63
  const int sgsw = tid & 7;             // stored granule
  const int G = sgsw ^ (srow & 7);      // unswizzled granule
  const int side = G >> 2, g2 = G & 3;  // which half / col granule
  const ushort_t* pA = A + (arow0 + (size_t)(side * 128 + srow)) * D_ + g2 * 8;
  const ushort_t* pB = Bt + (bcol0 + (size_t)((side * 2 + (srow >> 5)) * 64 + (srow & 31))) * D_ + g2 * 8;

  // prologue: tile 0 into dbuf 0, order B0,B1,A0,A1
  gload_lds16(pB, &lds[16384 + wid * 512]);
  gload_lds16(pB + 32 * D_, &lds[16384 + 4096 + wid * 512]);
  gload_lds16(pA, &lds[wid * 512]);
  gload_lds16(pA + 64 * D_, &lds[4096 + wid * 512]);

  f32x4 acc[8][4] = {};
  for (int kt = 0; kt < 32; ++kt) {
    const int d = kt & 1, nd = d ^ 1;
    const int kn = (kt < 31 ? kt + 1 : 31) * 32;  // clamped next-tile col offset
    bfrag ar[4], br[4];
    // ---------------- phase 0 ----------------
    gload_lds16(pB + kn, &lds[16384 + nd * 8192 + wid * 512]);
    gload_lds16(pB + 32 * D_ + kn, &lds[16384 + nd * 8192 + 4096 + wid * 512]);
    asm volatile("s_waitcnt vmcnt(3)" ::: "memory");
    __builtin_amdgcn_s_barrier();
    __builtin_amdgcn_sched_barrier(0);
#pragma unroll
    for (int mf2 = 0; mf2 < 4; ++mf2) {
      const int i = mf2 * 16 + frow;
      const int gsw = (wm * 4 + klo) ^ (i & 7);
      ar[mf2] = *(const bfrag*)&lds[d * 8192 + i * 64 + gsw * 8];
    }
#pragma unroll
    for (int nf = 0; nf < 4; ++nf) {
      const int p1 = nf >> 1;
      const int t = (wn & 1) * 32 + (nf & 1) * 16 + frow;
      const int gsw = ((wn >> 1) * 4 + klo) ^ (t & 7);
      br[nf] = *(const bfrag*)&lds[16384 + d * 8192 + p1 * 4096 + t * 64 + gsw * 8];
    }
    __builtin_amdgcn_s_setprio(1);
#pragma unroll
    for (int mf2 = 0; mf2 < 4; ++mf2)
#pragma unroll
      for (int nf = 0; nf < 4; ++nf)
        acc[mf2][nf] = mfma16x16x32(ar[mf2], br[nf], acc[mf2][nf]);
    __builtin_amdgcn_s_setprio(0);
    // ---------------- phase 1 ----------------
    gload_lds16(pA + kn, &lds[nd * 8192 + wid * 512]);
    gload_lds16(pA + 64 * D_ + kn, &lds[nd * 8192 + 4096 + wid * 512]);
    asm volatile("s_waitcnt vmcnt(4)" ::: "memory");
    __builtin_amdgcn_s_barrier();
    __builtin_amdgcn_sched_barrier(0);
#pragma unroll
    for (int mf2 = 0; mf2 < 4; ++mf2) {
      const int i = mf2 * 16 + frow;
      const int gsw = (wm * 4 + klo) ^ (i & 7);
      ar[mf2] = *(const bfrag*)&lds[d * 8192 + 4096 + i * 64 + gsw * 8];
    }
    __builtin_amdgcn_s_setprio(1);
#pragma unroll
    for (int mf2 = 0; mf2 < 4; ++mf2)
#pragma unroll
      for (int nf = 0; nf < 4; ++nf)
        acc[4 + mf2][nf] = mfma16x16x32(ar[mf2], br[nf], acc[4 + mf2][nf]);
    __builtin_amdgcn_s_setprio(0);
    __builtin_amdgcn_s_barrier();   // all reads of buf[d] landed before next tile stages it
  }
  asm volatile("s_waitcnt vmcnt(0)" ::: "memory");
  __builtin_amdgcn_s_barrier();
  __builtin_amdgcn_sched_barrier(0);

  if constexpr (MODE == 0) {
    // ---------------- epilogue: fp32 C store ----------------
    float* C = (float*)Cout;
#pragma unroll
    for (int m = 0; m < 8; ++m)
#pragma unroll
      for (int n = 0; n < 4; ++n)
#pragma unroll
        for (int r = 0; r < 4; ++r)
          C[(arow0 + wm * 128 + m * 16 + klo * 4 + r) * 1024 + bcol0 + wn * 64 + n * 16 + frow] =
              acc[m][n][r];
  } else {
    // ---------------- epilogue: fused attention (wave-private) ----------------
    ushort_t* W = &lds[wid * 4096];  // [64][64] bf16, granule ^= fsw(row)
    ushort_t* out1 = (ushort_t*)Cout;
    const int head = nblk * 4 + wn;
    const int bbatch = mblk >> 4;
    const size_t kvbase = ((size_t)bbatch * H_ + head) * (size_t)(S_ * DH_);
    bfrag kb[4][2], vb[4][2];
#pragma unroll
    for (int nf = 0; nf < 4; ++nf)
#pragma unroll
      for (int kk = 0; kk < 2; ++kk) {
        kb[nf][kk] = *(const bfrag*)&kbuf[kvbase + (nf * 16 + frow) * 64 + kk * 32 + klo * 8];
        vb[nf][kk] = *(const bfrag*)&vbuf[kvbase + (nf * 16 + frow) * 64 + kk * 32 + klo * 8];
      }
#pragma unroll
    for (int hh = 0; hh < 2; ++hh) {
      // q -> W (bf16, swizzled)
#pragma unroll
      for (int m2 = 0; m2 < 4; ++m2)
#pragma unroll
        for (int r = 0; r < 4; ++r) {
          const int row = m2 * 16 + klo * 4 + r;
          const int fs = fsw(row);
#pragma unroll
          for (int n = 0; n < 4; ++n) {
            const int cc = n * 16 + frow;
            W[row * 64 + ((((cc >> 3) ^ fs) << 3) | (cc & 7))] = f2bf(acc[hh * 4 + m2][n][r]);
          }
        }
      // sim = q @ K^T
      f32x4 s[4][4] = {};
#pragma unroll
      for (int m2 = 0; m2 < 4; ++m2) {
        const int row = m2 * 16 + frow;
        const int fs = fsw(row);
#pragma unroll
        for (int kk = 0; kk < 2; ++kk) {
          bfrag qa = *(const bfrag*)&W[row * 64 + (((kk * 4 + klo) ^ fs) << 3)];
#pragma unroll
          for (int nf = 0; nf < 4; ++nf)
            s[m2][nf] = mfma16x16x32(qa, kb[nf][kk], s[m2][nf]);
        }
      }
      // softmax over 64 keys (row in one 16-lane group, 4 keys/lane/frag)
#pragma unroll
      for (int m2 = 0; m2 < 4; ++m2)
#pragma unroll
        for (int r = 0; r < 4; ++r) {
          float a0 = s[m2][0][r], a1 = s[m2][1][r], a2 = s[m2][2][r], a3 = s[m2][3][r];
          float mx = fmaxf(fmaxf(a0, a1), fmaxf(a2, a3));
#pragma unroll
          for (int o = 1; o < 16; o <<= 1) mx = fmaxf(mx, __shfl_xor(mx, o));
          a0 = __expf(a0 - mx); a1 = __expf(a1 - mx);
          a2 = __expf(a2 - mx); a3 = __expf(a3 - mx);
          float sm = (a0 + a1) + (a2 + a3);
#pragma unroll
          for (int o = 1; o < 16; o <<= 1) sm += __shfl_xor(sm, o);
          const float inv = 1.0f / sm;
          s[m2][0][r] = a0 * inv; s[m2][1][r] = a1 * inv;
          s[m2][2][r] = a2 * inv; s[m2][3][r] = a3 * inv;
        }
      // P -> W (overwrite q; wave-private, in-order LDS)
#pragma unroll
      for (int m2 = 0; m2 < 4; ++m2)
#pragma unroll
        for (int r = 0; r < 4; ++r) {
          const int row = m2 * 16 + klo * 4 + r;
          const int fs = fsw(row);
#pragma unroll
          for (int n = 0; n < 4; ++n) {
            const int cc = n * 16 + frow;
            W[row * 64 + ((((cc >> 3) ^ fs) << 3) | (cc & 7))] = f2bf(s[m2][n][r]);
          }
        }
      // out1_half = attn @ "V^T" (einsum quirk: contract attn-keys with V dims)
      f32x4 o[4][4] = {};
#pragma unroll
      for (int m2 = 0; m2 < 4; ++m2) {
        const int row = m2 * 16 + frow;
        const int fs = fsw(row);
#pragma unroll
        for (int kk = 0; kk < 2; ++kk) {
          bfrag pa = *(const bfrag*)&W[row * 64 + (((kk * 4 + klo) ^ fs) << 3)];
#pragma unroll
          for (int nf = 0; nf < 4; ++nf)
            o[m2][nf] = mfma16x16x32(pa, vb[nf][kk], o[m2][nf]);
        }
      }
      // o -> W then coalesced uint4 stores
#pragma unroll
      for (int m2 = 0; m2 < 4; ++m2)
#pragma unroll
        for (int r = 0; r < 4; ++r) {
          const int row = m2 * 16 + klo * 4 + r;
          const int fs = fsw(row);
#pragma unroll
          for (int n = 0; n < 4; ++n) {
            const int cc = n * 16 + frow;
            W[row * 64 + ((((cc >> 3) ^ fs) << 3) | (cc & 7))] = f2bf(o[m2][n][r]);
          }
        }
      const size_t grow0 = arow0 + wm * 128 + hh * 64;
#pragma unroll
      for (int it = 0; it < 8; ++it) {
        const int idx = it * 64 + lane;
        const int rr = idx >> 3, gs = idx & 7;
        const int gcol = (gs ^ fsw(rr)) << 3;
        *(uint4*)&out1[(grow0 + rr) * 1024 + head * 64 + gcol] =
            *(const uint4*)&W[rr * 64 + gs * 8];
      }
    }
  }
}

// -------------------------------- launch --------------------------------
extern "C" void kernel_launch(void* const* d_in, const int* in_sizes, int n_in,
                              void* d_out, int out_size, void* d_ws, size_t ws_size,
                              hipStream_t stream) {
  const float* x = (const float*)d_in[0];
  const float* lat = (const float*)d_in[1];
  const float* lxg = (const float*)d_in[2];
  const float* lxb = (const float*)d_in[3];
  const float* llg = (const float*)d_in[4];
  const float* llb = (const float*)d_in[5];
  const float* Wq = (const float*)d_in[6];
  const float* Wkv = (const float*)d_in[7];
  const float* Wout = (const float*)d_in[8];
  float* out = (float*)d_out;
  char* ws = (char*)d_ws;

  // ws layout (142MB): xn 2MB | wqT 2MB | wkvT 4MB | woT 2MB | k 2MB | v 2MB | out1 128MB
  ushort_t* xn = (ushort_t*)(ws);
  ushort_t* wqT = (ushort_t*)(ws + (2ull << 20));
  ushort_t* wkvT = (ushort_t*)(ws + (4ull << 20));
  ushort_t* woT = (ushort_t*)(ws + (8ull << 20));
  ushort_t* kbuf = (ushort_t*)(ws + (10ull << 20));
  ushort_t* vbuf = (ushort_t*)(ws + (12ull << 20));
  ushort_t* out1 = (ushort_t*)(ws + (14ull << 20));
  // lnl (bf16, 128MB) lives in d_out's first half: dead before final GEMM writes d_out
  ushort_t* lnl = (ushort_t*)d_out;

  dim3 tb(32, 8);
  transpose_cast_kernel<<<dim3(1024 / 32, 32), tb, 0, stream>>>(Wq, wqT, 1024, 0.125f);
  transpose_cast_kernel<<<dim3(2048 / 32, 32), tb, 0, stream>>>(Wkv, wkvT, 2048, 1.0f);
  transpose_cast_kernel<<<dim3(1024 / 32, 32), tb, 0, stream>>>(Wout, woT, 1024, 1.0f);
  ln_rows_kernel<<<B_ * S_, 256, 0, stream>>>(x, lxg, lxb, xn);
  ln_rows_kernel<<<B_ * M_, 256, 0, stream>>>(lat, llg, llb, lnl);
  gemm_kv_kernel<<<dim3(8, 16), 256, 0, stream>>>(xn, wkvT, kbuf, vbuf);
  gemm256_kernel<1><<<1024, 512, 0, stream>>>(lnl, wqT, kbuf, vbuf, out1);
  gemm256_kernel<0><<<1024, 512, 0, stream>>>(out1, woT, nullptr, nullptr, out);
}

// Round 4
// 477.125 us; speedup vs baseline: 1.4058x; 1.0170x over previous
//
#include <hip/hip_runtime.h>
#include <stdint.h>

#define B_ 16
#define S_ 64
#define M_ 4096
#define D_ 1024
#define H_ 16
#define DH_ 64

typedef unsigned short ushort_t;
typedef __attribute__((ext_vector_type(8))) __bf16 bfrag;   // 8 bf16 = 4 VGPRs
typedef __attribute__((ext_vector_type(4))) float f32x4;

// fp32 -> bf16 RNE
__device__ __forceinline__ ushort_t f2bf(float f) {
  union { float f; uint32_t u; } v; v.f = f;
  uint32_t r = v.u + 0x7fffu + ((v.u >> 16) & 1u);
  return (ushort_t)(r >> 16);
}

__device__ __forceinline__ void gload_lds16(const void* g, void* l) {
  __builtin_amdgcn_global_load_lds((const __attribute__((address_space(1))) void*)g,
                                   (__attribute__((address_space(3))) void*)l, 16, 0, 0);
}

__device__ __forceinline__ f32x4 mfma16x16x32(bfrag a, bfrag b, f32x4 c) {
  return __builtin_amdgcn_mfma_f32_16x16x32_bf16(a, b, c, 0, 0, 0);
}

// epilogue-region swizzle: granule ^= fsw(row); fsw>>1 injective over klo groups
__device__ __forceinline__ int fsw(int r) { return (((r >> 2) & 3) << 1) | (r & 1); }

// ---------------- LayerNorm rows (1024 wide) -> bf16 ----------------
__global__ __launch_bounds__(256) void ln_rows_kernel(
    const float* __restrict__ x, const float* __restrict__ g,
    const float* __restrict__ bta, ushort_t* __restrict__ out) {
  const int row = blockIdx.x;
  const int t = threadIdx.x;
  const float4* xr = (const float4*)(x + (size_t)row * D_);
  float4 v = xr[t];
  float s = v.x + v.y + v.z + v.w;
  float ss = v.x * v.x + v.y * v.y + v.z * v.z + v.w * v.w;
#pragma unroll
  for (int o = 32; o >= 1; o >>= 1) { s += __shfl_down(s, o); ss += __shfl_down(ss, o); }
  __shared__ float red[16];
  const int wid = t >> 6;
  if ((t & 63) == 0) { red[wid] = s; red[8 + wid] = ss; }
  __syncthreads();
  float tot = red[0] + red[1] + red[2] + red[3];
  float tot2 = red[8] + red[9] + red[10] + red[11];
  float mu = tot * (1.0f / D_);
  float var = tot2 * (1.0f / D_) - mu * mu;
  float rstd = rsqrtf(var + 1e-5f);
  float4 gg = ((const float4*)g)[t];
  float4 bb = ((const float4*)bta)[t];
  ushort_t ob[4];
  ob[0] = f2bf((v.x - mu) * rstd * gg.x + bb.x);
  ob[1] = f2bf((v.y - mu) * rstd * gg.y + bb.y);
  ob[2] = f2bf((v.z - mu) * rstd * gg.z + bb.z);
  ob[3] = f2bf((v.w - mu) * rstd * gg.w + bb.w);
  *(uint2*)(out + (size_t)row * D_ + t * 4) = *(const uint2*)ob;
}

// ---------------- W[K=1024][N] fp32 -> WT[N][1024] bf16 (scaled) ----------------
__global__ void transpose_cast_kernel(const float* __restrict__ W, ushort_t* __restrict__ WT,
                                      int N, float scale) {
  __shared__ float tile[32][33];
  const int n0 = blockIdx.x * 32, k0 = blockIdx.y * 32;
  const int tx = threadIdx.x, ty = threadIdx.y;
#pragma unroll
  for (int i = ty; i < 32; i += 8)
    tile[i][tx] = W[(size_t)(k0 + i) * N + n0 + tx];
  __syncthreads();
#pragma unroll
  for (int i = ty; i < 32; i += 8)
    WT[(size_t)(n0 + i) * D_ + k0 + tx] = f2bf(tile[tx][i] * scale);
}

// ---------------- kv GEMM (small, 4.3 GF): 128x128, scatter to (b,h,s,d) ----------
__global__ __launch_bounds__(256) void gemm_kv_kernel(
    const ushort_t* __restrict__ A, const ushort_t* __restrict__ Bt,
    ushort_t* __restrict__ kb, ushort_t* __restrict__ vb) {
  __shared__ __align__(16) ushort_t sA[128 * 32];
  __shared__ __align__(16) ushort_t sB[128 * 32];
  const int tid = threadIdx.x, wid = tid >> 6, lane = tid & 63;
  const size_t arow0 = (size_t)blockIdx.x * 128;
  const size_t brow0 = (size_t)blockIdx.y * 128;
  const int wr = (wid >> 1) * 64, wc = (wid & 1) * 64;
  const int srow = tid >> 2, scol = (tid & 3) * 8;
  const ushort_t* ga = A + (arow0 + srow) * (size_t)D_ + scol;
  const ushort_t* gb = Bt + (brow0 + srow) * (size_t)D_ + scol;
  const int frow = lane & 15, kslot = (lane >> 4) * 8;
  f32x4 acc[4][4] = {};
  for (int k0 = 0; k0 < D_; k0 += 32) {
    gload_lds16(ga, sA + wid * 512);
    gload_lds16(ga + 64 * (size_t)D_, sA + 2048 + wid * 512);
    gload_lds16(gb, sB + wid * 512);
    gload_lds16(gb + 64 * (size_t)D_, sB + 2048 + wid * 512);
    ga += 32; gb += 32;
    __syncthreads();
    bfrag af[4], bfv[4];
#pragma unroll
    for (int m = 0; m < 4; ++m)
      af[m] = *(const bfrag*)&sA[(wr + m * 16 + frow) * 32 + kslot];
#pragma unroll
    for (int n = 0; n < 4; ++n)
      bfv[n] = *(const bfrag*)&sB[(wc + n * 16 + frow) * 32 + kslot];
#pragma unroll
    for (int m = 0; m < 4; ++m)
#pragma unroll
      for (int n = 0; n < 4; ++n)
        acc[m][n] = mfma16x16x32(af[m], bfv[n], acc[m][n]);
    __syncthreads();
  }
  const int erow = (lane >> 4) * 4, ecol = lane & 15;
#pragma unroll
  for (int m = 0; m < 4; ++m)
#pragma unroll
    for (int n = 0; n < 4; ++n)
#pragma unroll
      for (int r = 0; r < 4; ++r) {
        size_t i = arow0 + wr + m * 16 + erow + r;
        int bb = (int)(i >> 6), s = (int)(i & 63);
        size_t n2 = brow0 + wc + n * 16 + ecol;
        ushort_t val = f2bf(acc[m][n][r]);
        ushort_t* dst = (n2 < 1024) ? kb : vb;
        size_t hh = (n2 & 1023) >> 6, d = n2 & 63;
        dst[(((size_t)bb * H_ + hh) * S_ + s) * DH_ + d] = val;
      }
}

// ============== 256x256 deep-pipelined GEMM, C = A * Bt^T =========================
// BK=32, 4-slot LDS ring per operand (128KB total), 8 waves (2m x 4n).
// Per K-tile: ONE barrier, vmcnt(8) (never 0 in-loop), stage tile kt+3 (4 gloads),
// 12 ds_read_b128 (2-way swizzle = free), 32 MFMA under setprio.
// Per-wave issue accounting: prologue 12; at tile kt's wait, issued = 12+4kt,
// vmcnt(8) retires positions <= 4kt+4 = exactly tile kt's loads (3-tile lead).
// MODE 0: epilogue = fp32 C store (out-projection)
// MODE 1: epilogue = fused attention per wave-half (head = nblk*4+wn), bf16 out1
template <int MODE>
__global__ __launch_bounds__(512, 2) void gemm256_kernel(
    const ushort_t* __restrict__ A, const ushort_t* __restrict__ Bt,
    const ushort_t* __restrict__ kbuf, const ushort_t* __restrict__ vbuf,
    void* __restrict__ Cout) {
  __shared__ __align__(16) ushort_t lds[65536];  // 128KB: A ring 64KB | B ring 64KB
  const int tid = threadIdx.x, wid = tid >> 6, lane = tid & 63;
  const int frow = lane & 15, klo = lane >> 4;
  const int wm = wid >> 2, wn = wid & 3;

  // XCD-swizzled block mapping (1024 = 8*128, bijective)
  const int l = ((int)blockIdx.x & 7) * 128 + ((int)blockIdx.x >> 3);
  const int mblk = l >> 2, nblk = l & 3;
  const size_t arow0 = (size_t)mblk * 256;
  const size_t bcol0 = (size_t)nblk * 256;

  // ---- per-thread staging constants (slot u = tid) ----
  const int srow = tid >> 3;            // pair-row 0..63
  const int sgsw = tid & 7;             // stored granule
  const int G = sgsw ^ (srow & 7);      // unswizzled granule
  const int side = G >> 2, g2 = G & 3;  // which half / col granule
  const ushort_t* pA = A + (arow0 + (size_t)(side * 128 + srow)) * D_ + g2 * 8;
  const ushort_t* pB = Bt + (bcol0 + (size_t)((side * 2 + (srow >> 5)) * 64 + (srow & 31))) * D_ + g2 * 8;

#define STAGE(KT)                                                                  \
  do {                                                                             \
    const int _s = (KT) & 3;                                                       \
    const size_t _kn = (size_t)(((KT) < 32 ? (KT) : 31)) * 32;                     \
    gload_lds16(pB + _kn, &lds[32768 + _s * 8192 + wid * 512]);                    \
    gload_lds16(pB + 32 * (size_t)D_ + _kn, &lds[32768 + _s * 8192 + 4096 + wid * 512]); \
    gload_lds16(pA + _kn, &lds[_s * 8192 + wid * 512]);                            \
    gload_lds16(pA + 64 * (size_t)D_ + _kn, &lds[_s * 8192 + 4096 + wid * 512]);   \
  } while (0)

  // prologue: stage tiles 0,1,2 (12 gloads per wave)
  STAGE(0);
  STAGE(1);
  STAGE(2);

  f32x4 acc[8][4] = {};
  for (int kt = 0; kt < 32; ++kt) {
    asm volatile("s_waitcnt vmcnt(8)" ::: "memory");
    __builtin_amdgcn_s_barrier();
    __builtin_amdgcn_sched_barrier(0);
    STAGE(kt + 3);  // into slot (kt-1)&3: safe, everyone passed the barrier
    const int sl = kt & 3;
    bfrag ar[8], br[4];
#pragma unroll
    for (int mf = 0; mf < 8; ++mf) {
      const int i = (mf & 3) * 16 + frow;
      const int gsw = (wm * 4 + klo) ^ (i & 7);
      ar[mf] = *(const bfrag*)&lds[sl * 8192 + (mf >> 2) * 4096 + i * 64 + gsw * 8];
    }
#pragma unroll
    for (int nf = 0; nf < 4; ++nf) {
      const int t = (wn & 1) * 32 + (nf & 1) * 16 + frow;
      const int gsw = ((wn >> 1) * 4 + klo) ^ (t & 7);
      br[nf] = *(const bfrag*)&lds[32768 + sl * 8192 + (nf >> 1) * 4096 + t * 64 + gsw * 8];
    }
    __builtin_amdgcn_s_setprio(1);
#pragma unroll
    for (int mf = 0; mf < 8; ++mf)
#pragma unroll
      for (int nf = 0; nf < 4; ++nf)
        acc[mf][nf] = mfma16x16x32(ar[mf], br[nf], acc[mf][nf]);
    __builtin_amdgcn_s_setprio(0);
  }
  // drain tail garbage-stages before reusing LDS / exiting
  asm volatile("s_waitcnt vmcnt(0)" ::: "memory");
  __builtin_amdgcn_s_barrier();
  __builtin_amdgcn_sched_barrier(0);
#undef STAGE

  if constexpr (MODE == 0) {
    // ---------------- epilogue: fp32 C store ----------------
    float* C = (float*)Cout;
#pragma unroll
    for (int m = 0; m < 8; ++m)
#pragma unroll
      for (int n = 0; n < 4; ++n)
#pragma unroll
        for (int r = 0; r < 4; ++r)
          C[(arow0 + wm * 128 + m * 16 + klo * 4 + r) * 1024 + bcol0 + wn * 64 + n * 16 + frow] =
              acc[m][n][r];
  } else {
    // ---------------- epilogue: fused attention (wave-private) ----------------
    ushort_t* W = &lds[wid * 4096];  // [64][64] bf16, granule ^= fsw(row)
    ushort_t* out1 = (ushort_t*)Cout;
    const int head = nblk * 4 + wn;
    const int bbatch = mblk >> 4;
    const size_t kvbase = ((size_t)bbatch * H_ + head) * (size_t)(S_ * DH_);
    bfrag kb[4][2], vb[4][2];
#pragma unroll
    for (int nf = 0; nf < 4; ++nf)
#pragma unroll
      for (int kk = 0; kk < 2; ++kk) {
        kb[nf][kk] = *(const bfrag*)&kbuf[kvbase + (nf * 16 + frow) * 64 + kk * 32 + klo * 8];
        vb[nf][kk] = *(const bfrag*)&vbuf[kvbase + (nf * 16 + frow) * 64 + kk * 32 + klo * 8];
      }
#pragma unroll
    for (int hh = 0; hh < 2; ++hh) {
      // q -> W (bf16, swizzled)
#pragma unroll
      for (int m2 = 0; m2 < 4; ++m2)
#pragma unroll
        for (int r = 0; r < 4; ++r) {
          const int row = m2 * 16 + klo * 4 + r;
          const int fs = fsw(row);
#pragma unroll
          for (int n = 0; n < 4; ++n) {
            const int cc = n * 16 + frow;
            W[row * 64 + ((((cc >> 3) ^ fs) << 3) | (cc & 7))] = f2bf(acc[hh * 4 + m2][n][r]);
          }
        }
      // sim = q @ K^T
      f32x4 s[4][4] = {};
#pragma unroll
      for (int m2 = 0; m2 < 4; ++m2) {
        const int row = m2 * 16 + frow;
        const int fs = fsw(row);
#pragma unroll
        for (int kk = 0; kk < 2; ++kk) {
          bfrag qa = *(const bfrag*)&W[row * 64 + (((kk * 4 + klo) ^ fs) << 3)];
#pragma unroll
          for (int nf = 0; nf < 4; ++nf)
            s[m2][nf] = mfma16x16x32(qa, kb[nf][kk], s[m2][nf]);
        }
      }
      // softmax over 64 keys (row in one 16-lane group, 4 keys/lane/frag)
#pragma unroll
      for (int m2 = 0; m2 < 4; ++m2)
#pragma unroll
        for (int r = 0; r < 4; ++r) {
          float a0 = s[m2][0][r], a1 = s[m2][1][r], a2 = s[m2][2][r], a3 = s[m2][3][r];
          float mx = fmaxf(fmaxf(a0, a1), fmaxf(a2, a3));
#pragma unroll
          for (int o = 1; o < 16; o <<= 1) mx = fmaxf(mx, __shfl_xor(mx, o));
          a0 = __expf(a0 - mx); a1 = __expf(a1 - mx);
          a2 = __expf(a2 - mx); a3 = __expf(a3 - mx);
          float sm = (a0 + a1) + (a2 + a3);
#pragma unroll
          for (int o = 1; o < 16; o <<= 1) sm += __shfl_xor(sm, o);
          const float inv = 1.0f / sm;
          s[m2][0][r] = a0 * inv; s[m2][1][r] = a1 * inv;
          s[m2][2][r] = a2 * inv; s[m2][3][r] = a3 * inv;
        }
      // P -> W (overwrite q; wave-private, in-order LDS)
#pragma unroll
      for (int m2 = 0; m2 < 4; ++m2)
#pragma unroll
        for (int r = 0; r < 4; ++r) {
          const int row = m2 * 16 + klo * 4 + r;
          const int fs = fsw(row);
#pragma unroll
          for (int n = 0; n < 4; ++n) {
            const int cc = n * 16 + frow;
            W[row * 64 + ((((cc >> 3) ^ fs) << 3) | (cc & 7))] = f2bf(s[m2][n][r]);
          }
        }
      // out1_half = attn @ "V^T" (einsum quirk: contract attn-keys with V dims)
      f32x4 o[4][4] = {};
#pragma unroll
      for (int m2 = 0; m2 < 4; ++m2) {
        const int row = m2 * 16 + frow;
        const int fs = fsw(row);
#pragma unroll
        for (int kk = 0; kk < 2; ++kk) {
          bfrag pa = *(const bfrag*)&W[row * 64 + (((kk * 4 + klo) ^ fs) << 3)];
#pragma unroll
          for (int nf = 0; nf < 4; ++nf)
            o[m2][nf] = mfma16x16x32(pa, vb[nf][kk], o[m2][nf]);
        }
      }
      // o -> W then coalesced uint4 stores
#pragma unroll
      for (int m2 = 0; m2 < 4; ++m2)
#pragma unroll
        for (int r = 0; r < 4; ++r) {
          const int row = m2 * 16 + klo * 4 + r;
          const int fs = fsw(row);
#pragma unroll
          for (int n = 0; n < 4; ++n) {
            const int cc = n * 16 + frow;
            W[row * 64 + ((((cc >> 3) ^ fs) << 3) | (cc & 7))] = f2bf(o[m2][n][r]);
          }
        }
      const size_t grow0 = arow0 + wm * 128 + hh * 64;
#pragma unroll
      for (int it = 0; it < 8; ++it) {
        const int idx = it * 64 + lane;
        const int rr = idx >> 3, gs = idx & 7;
        const int gcol = (gs ^ fsw(rr)) << 3;
        *(uint4*)&out1[(grow0 + rr) * 1024 + head * 64 + gcol] =
            *(const uint4*)&W[rr * 64 + gs * 8];
      }
    }
  }
}

// -------------------------------- launch --------------------------------
extern "C" void kernel_launch(void* const* d_in, const int* in_sizes, int n_in,
                              void* d_out, int out_size, void* d_ws, size_t ws_size,
                              hipStream_t stream) {
  const float* x = (const float*)d_in[0];
  const float* lat = (const float*)d_in[1];
  const float* lxg = (const float*)d_in[2];
  const float* lxb = (const float*)d_in[3];
  const float* llg = (const float*)d_in[4];
  const float* llb = (const float*)d_in[5];
  const float* Wq = (const float*)d_in[6];
  const float* Wkv = (const float*)d_in[7];
  const float* Wout = (const float*)d_in[8];
  float* out = (float*)d_out;
  char* ws = (char*)d_ws;

  // ws layout (142MB): xn 2MB | wqT 2MB | wkvT 4MB | woT 2MB | k 2MB | v 2MB | out1 128MB
  ushort_t* xn = (ushort_t*)(ws);
  ushort_t* wqT = (ushort_t*)(ws + (2ull << 20));
  ushort_t* wkvT = (ushort_t*)(ws + (4ull << 20));
  ushort_t* woT = (ushort_t*)(ws + (8ull << 20));
  ushort_t* kbuf = (ushort_t*)(ws + (10ull << 20));
  ushort_t* vbuf = (ushort_t*)(ws + (12ull << 20));
  ushort_t* out1 = (ushort_t*)(ws + (14ull << 20));
  // lnl (bf16, 128MB) lives in d_out's first half: dead before final GEMM writes d_out
  ushort_t* lnl = (ushort_t*)d_out;

  dim3 tb(32, 8);
  transpose_cast_kernel<<<dim3(1024 / 32, 32), tb, 0, stream>>>(Wq, wqT, 1024, 0.125f);
  transpose_cast_kernel<<<dim3(2048 / 32, 32), tb, 0, stream>>>(Wkv, wkvT, 2048, 1.0f);
  transpose_cast_kernel<<<dim3(1024 / 32, 32), tb, 0, stream>>>(Wout, woT, 1024, 1.0f);
  ln_rows_kernel<<<B_ * S_, 256, 0, stream>>>(x, lxg, lxb, xn);
  ln_rows_kernel<<<B_ * M_, 256, 0, stream>>>(lat, llg, llb, lnl);
  gemm_kv_kernel<<<dim3(8, 16), 256, 0, stream>>>(xn, wkvT, kbuf, vbuf);
  gemm256_kernel<1><<<1024, 512, 0, stream>>>(lnl, wqT, kbuf, vbuf, out1);
  gemm256_kernel<0><<<1024, 512, 0, stream>>>(out1, woT, nullptr, nullptr, out);
}

// Round 5
// 472.703 us; speedup vs baseline: 1.4190x; 1.0094x over previous
//
#include <hip/hip_runtime.h>
#include <stdint.h>

#define B_ 16
#define S_ 64
#define M_ 4096
#define D_ 1024
#define H_ 16
#define DH_ 64

typedef unsigned short ushort_t;
typedef __attribute__((ext_vector_type(8))) __bf16 bfrag;   // 8 bf16 = 4 VGPRs
typedef __attribute__((ext_vector_type(4))) float f32x4;

// fp32 -> bf16 RNE
__device__ __forceinline__ ushort_t f2bf(float f) {
  union { float f; uint32_t u; } v; v.f = f;
  uint32_t r = v.u + 0x7fffu + ((v.u >> 16) & 1u);
  return (ushort_t)(r >> 16);
}

__device__ __forceinline__ void gload_lds16(const void* g, void* l) {
  __builtin_amdgcn_global_load_lds((const __attribute__((address_space(1))) void*)g,
                                   (__attribute__((address_space(3))) void*)l, 16, 0, 0);
}

__device__ __forceinline__ f32x4 mfma16x16x32(bfrag a, bfrag b, f32x4 c) {
  return __builtin_amdgcn_mfma_f32_16x16x32_bf16(a, b, c, 0, 0, 0);
}

// epilogue-region swizzle: granule ^= fsw(row); fsw>>1 injective over klo groups
__device__ __forceinline__ int fsw(int r) { return (((r >> 2) & 3) << 1) | (r & 1); }

// ---------------- LayerNorm rows (1024 wide) -> bf16 ----------------
__global__ __launch_bounds__(256) void ln_rows_kernel(
    const float* __restrict__ x, const float* __restrict__ g,
    const float* __restrict__ bta, ushort_t* __restrict__ out) {
  const int row = blockIdx.x;
  const int t = threadIdx.x;
  const float4* xr = (const float4*)(x + (size_t)row * D_);
  float4 v = xr[t];
  float s = v.x + v.y + v.z + v.w;
  float ss = v.x * v.x + v.y * v.y + v.z * v.z + v.w * v.w;
#pragma unroll
  for (int o = 32; o >= 1; o >>= 1) { s += __shfl_down(s, o); ss += __shfl_down(ss, o); }
  __shared__ float red[16];
  const int wid = t >> 6;
  if ((t & 63) == 0) { red[wid] = s; red[8 + wid] = ss; }
  __syncthreads();
  float tot = red[0] + red[1] + red[2] + red[3];
  float tot2 = red[8] + red[9] + red[10] + red[11];
  float mu = tot * (1.0f / D_);
  float var = tot2 * (1.0f / D_) - mu * mu;
  float rstd = rsqrtf(var + 1e-5f);
  float4 gg = ((const float4*)g)[t];
  float4 bb = ((const float4*)bta)[t];
  ushort_t ob[4];
  ob[0] = f2bf((v.x - mu) * rstd * gg.x + bb.x);
  ob[1] = f2bf((v.y - mu) * rstd * gg.y + bb.y);
  ob[2] = f2bf((v.z - mu) * rstd * gg.z + bb.z);
  ob[3] = f2bf((v.w - mu) * rstd * gg.w + bb.w);
  *(uint2*)(out + (size_t)row * D_ + t * 4) = *(const uint2*)ob;
}

// ---------------- W[K=1024][N] fp32 -> WT[N][1024] bf16 (scaled) ----------------
__global__ void transpose_cast_kernel(const float* __restrict__ W, ushort_t* __restrict__ WT,
                                      int N, float scale) {
  __shared__ float tile[32][33];
  const int n0 = blockIdx.x * 32, k0 = blockIdx.y * 32;
  const int tx = threadIdx.x, ty = threadIdx.y;
#pragma unroll
  for (int i = ty; i < 32; i += 8)
    tile[i][tx] = W[(size_t)(k0 + i) * N + n0 + tx];
  __syncthreads();
#pragma unroll
  for (int i = ty; i < 32; i += 8)
    WT[(size_t)(n0 + i) * D_ + k0 + tx] = f2bf(tile[tx][i] * scale);
}

// ---------------- kv GEMM (small, 4.3 GF): 128x128, scatter to (b,h,s,d) ----------
__global__ __launch_bounds__(256) void gemm_kv_kernel(
    const ushort_t* __restrict__ A, const ushort_t* __restrict__ Bt,
    ushort_t* __restrict__ kb, ushort_t* __restrict__ vb) {
  __shared__ __align__(16) ushort_t sA[128 * 32];
  __shared__ __align__(16) ushort_t sB[128 * 32];
  const int tid = threadIdx.x, wid = tid >> 6, lane = tid & 63;
  const size_t arow0 = (size_t)blockIdx.x * 128;
  const size_t brow0 = (size_t)blockIdx.y * 128;
  const int wr = (wid >> 1) * 64, wc = (wid & 1) * 64;
  const int srow = tid >> 2, scol = (tid & 3) * 8;
  const ushort_t* ga = A + (arow0 + srow) * (size_t)D_ + scol;
  const ushort_t* gb = Bt + (brow0 + srow) * (size_t)D_ + scol;
  const int frow = lane & 15, kslot = (lane >> 4) * 8;
  f32x4 acc[4][4] = {};
  for (int k0 = 0; k0 < D_; k0 += 32) {
    gload_lds16(ga, sA + wid * 512);
    gload_lds16(ga + 64 * (size_t)D_, sA + 2048 + wid * 512);
    gload_lds16(gb, sB + wid * 512);
    gload_lds16(gb + 64 * (size_t)D_, sB + 2048 + wid * 512);
    ga += 32; gb += 32;
    __syncthreads();
    bfrag af[4], bfv[4];
#pragma unroll
    for (int m = 0; m < 4; ++m)
      af[m] = *(const bfrag*)&sA[(wr + m * 16 + frow) * 32 + kslot];
#pragma unroll
    for (int n = 0; n < 4; ++n)
      bfv[n] = *(const bfrag*)&sB[(wc + n * 16 + frow) * 32 + kslot];
#pragma unroll
    for (int m = 0; m < 4; ++m)
#pragma unroll
      for (int n = 0; n < 4; ++n)
        acc[m][n] = mfma16x16x32(af[m], bfv[n], acc[m][n]);
    __syncthreads();
  }
  const int erow = (lane >> 4) * 4, ecol = lane & 15;
#pragma unroll
  for (int m = 0; m < 4; ++m)
#pragma unroll
    for (int n = 0; n < 4; ++n)
#pragma unroll
      for (int r = 0; r < 4; ++r) {
        size_t i = arow0 + wr + m * 16 + erow + r;
        int bb = (int)(i >> 6), s = (int)(i & 63);
        size_t n2 = brow0 + wc + n * 16 + ecol;
        ushort_t val = f2bf(acc[m][n][r]);
        ushort_t* dst = (n2 < 1024) ? kb : vb;
        size_t hh = (n2 & 1023) >> 6, d = n2 & 63;
        dst[(((size_t)bb * H_ + hh) * S_ + s) * DH_ + d] = val;
      }
}

// ============== 256x256 8-phase-template GEMM, C = A * Bt^T ========================
// BK=64 K-tiles as 2 K-halves (ghalf g = K cols [g*32, g*32+32), 16KB slot).
// Ring: 4 slots/operand (A at 0, B at 32768 ushorts), slot = g & 3. 128KB LDS.
// 8 waves (2m x 4n), per-wave 128x64 out = 8m x 4n frags.
// Per K-tile 4 phases (kh, mh): each = { stage ONE half-tile (2 gloads);
//   ds_read 4 A-frags (+4 B-frags at mh==0); [vmcnt(8) at phases 2,4];
//   bar; lgkmcnt(0); setprio(1); 16 MFMA; setprio(0); bar }.
// Loads stay 3-4 half-tiles in flight across barriers (counted vmcnt, never 0).
// Slot reuse is issue-after-free: stage of ghalf g+3/g+4 issues >=1 phase after
// the slot's previous occupant's last ds_read phase. Slot index uses UNCLAMPED g.
// K-half LDS row = 64B; swizzle gidx = klo ^ ((row>>1)&3) -> 2-way reads (free).
// MODE 0: epilogue = fp32 C store (out-projection)
// MODE 1: epilogue = fused attention per wave-half (head = nblk*4+wn), bf16 out1
template <int MODE>
__global__ __launch_bounds__(512, 2) void gemm256_kernel(
    const ushort_t* __restrict__ A, const ushort_t* __restrict__ Bt,
    const ushort_t* __restrict__ kbuf, const ushort_t* __restrict__ vbuf,
    void* __restrict__ Cout) {
  __shared__ __align__(16) ushort_t lds[65536];  // 128KB: A ring 64KB | B ring 64KB
  const int tid = threadIdx.x, wid = tid >> 6, lane = tid & 63;
  const int frow = lane & 15, klo = lane >> 4;
  const int wm = wid >> 2, wn = wid & 3;

  // XCD-swizzled block mapping (1024 = 8*128, bijective)
  const int l = ((int)blockIdx.x & 7) * 128 + ((int)blockIdx.x >> 3);
  const int mblk = l >> 2, nblk = l & 3;
  const size_t arow0 = (size_t)mblk * 256;
  const size_t bcol0 = (size_t)nblk * 256;

  // ---- staging constants: thread covers (row, gidx) = (d8>>2, d8&3), d8=j*512+tid
  // stored granule gidx holds source granule gidx ^ ((row>>1)&3)
  const int r0 = tid >> 2;                              // rows j*128 + r0
  const int gsrc = (tid & 3) ^ ((tid >> 3) & 3);
  const ushort_t* pA0 = A + (arow0 + r0) * (size_t)D_ + gsrc * 8;
  const ushort_t* pA1 = pA0 + (size_t)128 * D_;
  const ushort_t* pB0 = Bt + (bcol0 + r0) * (size_t)D_ + gsrc * 8;
  const ushort_t* pB1 = pB0 + (size_t)128 * D_;
  // ds_read swizzled granule offset (constant per lane; (row>>1)&3 == (frow>>1)&3)
  const int rasw = (klo ^ ((frow >> 1) & 3)) * 8;

#define STAGE_A(G)                                                            \
  do {                                                                        \
    const int s_ = (G) & 3;                                                   \
    const size_t ko_ = (size_t)((G) < 32 ? (G) : 31) * 32;                    \
    gload_lds16(pA0 + ko_, &lds[s_ * 8192 + wid * 512]);                      \
    gload_lds16(pA1 + ko_, &lds[s_ * 8192 + 4096 + wid * 512]);               \
  } while (0)
#define STAGE_B(G)                                                            \
  do {                                                                        \
    const int s_ = (G) & 3;                                                   \
    const size_t ko_ = (size_t)((G) < 32 ? (G) : 31) * 32;                    \
    gload_lds16(pB0 + ko_, &lds[32768 + s_ * 8192 + wid * 512]);              \
    gload_lds16(pB1 + ko_, &lds[32768 + s_ * 8192 + 4096 + wid * 512]);       \
  } while (0)

  // phase: stage 1 half-tile, read frags, (wait), bar, lgkm0, 16 MFMA, bar
#define PHASE(KH, MH, STAGE_STMT, DO_WAIT)                                    \
  do {                                                                        \
    STAGE_STMT;                                                               \
    const ushort_t* As_ = &lds[((2 * t + (KH)) & 3) * 8192];                  \
    if ((MH) == 0) {                                                          \
      const ushort_t* Bs_ = &lds[32768 + ((2 * t + (KH)) & 3) * 8192];        \
      _Pragma("unroll") for (int nf = 0; nf < 4; ++nf)                        \
          bregs[nf] = *(const bfrag*)&Bs_[(wn * 64 + nf * 16 + frow) * 32 + rasw]; \
    }                                                                         \
    bfrag a_[4];                                                              \
    _Pragma("unroll") for (int mf = 0; mf < 4; ++mf)                          \
        a_[mf] = *(const bfrag*)&As_[(wm * 128 + (MH) * 64 + mf * 16 + frow) * 32 + rasw]; \
    if (DO_WAIT) asm volatile("s_waitcnt vmcnt(8)" ::: "memory");             \
    __builtin_amdgcn_s_barrier();                                             \
    asm volatile("s_waitcnt lgkmcnt(0)" ::: "memory");                        \
    __builtin_amdgcn_sched_barrier(0);                                        \
    __builtin_amdgcn_s_setprio(1);                                            \
    _Pragma("unroll") for (int mf = 0; mf < 4; ++mf)                          \
        _Pragma("unroll") for (int nf = 0; nf < 4; ++nf)                      \
            acc[(MH) * 4 + mf][nf] =                                          \
                mfma16x16x32(a_[mf], bregs[nf], acc[(MH) * 4 + mf][nf]);      \
    __builtin_amdgcn_s_setprio(0);                                            \
    __builtin_amdgcn_s_barrier();                                             \
  } while (0)

  // prologue: ghalfs 0,1,2 for A and B (12 loads/thread); vmcnt(8) => {A,B}(0) landed
  STAGE_A(0); STAGE_B(0);
  STAGE_A(1); STAGE_B(1);
  STAGE_A(2); STAGE_B(2);
  asm volatile("s_waitcnt vmcnt(8)" ::: "memory");
  __builtin_amdgcn_s_barrier();

  f32x4 acc[8][4] = {};
  bfrag bregs[4];
  for (int t = 0; t < 16; ++t) {
    PHASE(0, 0, STAGE_A(2 * t + 3), 0);
    PHASE(0, 1, STAGE_B(2 * t + 3), 1);
    PHASE(1, 0, STAGE_A(2 * t + 4), 0);
    PHASE(1, 1, STAGE_B(2 * t + 4), 1);
  }
  // drain tail stages before reusing LDS / exiting
  asm volatile("s_waitcnt vmcnt(0)" ::: "memory");
  __builtin_amdgcn_s_barrier();
  __builtin_amdgcn_sched_barrier(0);
#undef PHASE
#undef STAGE_A
#undef STAGE_B

  if constexpr (MODE == 0) {
    // ---------------- epilogue: fp32 C store (acc[m] rows = m*16 + klo*4 + r) -----
    float* C = (float*)Cout;
#pragma unroll
    for (int m = 0; m < 8; ++m)
#pragma unroll
      for (int n = 0; n < 4; ++n)
#pragma unroll
        for (int r = 0; r < 4; ++r)
          C[(arow0 + wm * 128 + m * 16 + klo * 4 + r) * 1024 + bcol0 + wn * 64 + n * 16 + frow] =
              acc[m][n][r];
  } else {
    // ---------------- epilogue: fused attention (wave-private) ----------------
    ushort_t* W = &lds[wid * 4096];  // [64][64] bf16, granule ^= fsw(row)
    ushort_t* out1 = (ushort_t*)Cout;
    const int head = nblk * 4 + wn;
    const int bbatch = mblk >> 4;
    const size_t kvbase = ((size_t)bbatch * H_ + head) * (size_t)(S_ * DH_);
    bfrag kb[4][2], vb[4][2];
#pragma unroll
    for (int nf = 0; nf < 4; ++nf)
#pragma unroll
      for (int kk = 0; kk < 2; ++kk) {
        kb[nf][kk] = *(const bfrag*)&kbuf[kvbase + (nf * 16 + frow) * 64 + kk * 32 + klo * 8];
        vb[nf][kk] = *(const bfrag*)&vbuf[kvbase + (nf * 16 + frow) * 64 + kk * 32 + klo * 8];
      }
#pragma unroll
    for (int hh = 0; hh < 2; ++hh) {
      // q -> W (bf16, swizzled)
#pragma unroll
      for (int m2 = 0; m2 < 4; ++m2)
#pragma unroll
        for (int r = 0; r < 4; ++r) {
          const int row = m2 * 16 + klo * 4 + r;
          const int fs = fsw(row);
#pragma unroll
          for (int n = 0; n < 4; ++n) {
            const int cc = n * 16 + frow;
            W[row * 64 + ((((cc >> 3) ^ fs) << 3) | (cc & 7))] = f2bf(acc[hh * 4 + m2][n][r]);
          }
        }
      // sim = q @ K^T
      f32x4 s[4][4] = {};
#pragma unroll
      for (int m2 = 0; m2 < 4; ++m2) {
        const int row = m2 * 16 + frow;
        const int fs = fsw(row);
#pragma unroll
        for (int kk = 0; kk < 2; ++kk) {
          bfrag qa = *(const bfrag*)&W[row * 64 + (((kk * 4 + klo) ^ fs) << 3)];
#pragma unroll
          for (int nf = 0; nf < 4; ++nf)
            s[m2][nf] = mfma16x16x32(qa, kb[nf][kk], s[m2][nf]);
        }
      }
      // softmax over 64 keys (row in one 16-lane group, 4 keys/lane/frag)
#pragma unroll
      for (int m2 = 0; m2 < 4; ++m2)
#pragma unroll
        for (int r = 0; r < 4; ++r) {
          float a0 = s[m2][0][r], a1 = s[m2][1][r], a2 = s[m2][2][r], a3 = s[m2][3][r];
          float mx = fmaxf(fmaxf(a0, a1), fmaxf(a2, a3));
#pragma unroll
          for (int o = 1; o < 16; o <<= 1) mx = fmaxf(mx, __shfl_xor(mx, o));
          a0 = __expf(a0 - mx); a1 = __expf(a1 - mx);
          a2 = __expf(a2 - mx); a3 = __expf(a3 - mx);
          float sm = (a0 + a1) + (a2 + a3);
#pragma unroll
          for (int o = 1; o < 16; o <<= 1) sm += __shfl_xor(sm, o);
          const float inv = 1.0f / sm;
          s[m2][0][r] = a0 * inv; s[m2][1][r] = a1 * inv;
          s[m2][2][r] = a2 * inv; s[m2][3][r] = a3 * inv;
        }
      // P -> W (overwrite q; wave-private, in-order LDS)
#pragma unroll
      for (int m2 = 0; m2 < 4; ++m2)
#pragma unroll
        for (int r = 0; r < 4; ++r) {
          const int row = m2 * 16 + klo * 4 + r;
          const int fs = fsw(row);
#pragma unroll
          for (int n = 0; n < 4; ++n) {
            const int cc = n * 16 + frow;
            W[row * 64 + ((((cc >> 3) ^ fs) << 3) | (cc & 7))] = f2bf(s[m2][n][r]);
          }
        }
      // out1_half = attn @ "V^T" (einsum quirk: contract attn-keys with V dims)
      f32x4 o[4][4] = {};
#pragma unroll
      for (int m2 = 0; m2 < 4; ++m2) {
        const int row = m2 * 16 + frow;
        const int fs = fsw(row);
#pragma unroll
        for (int kk = 0; kk < 2; ++kk) {
          bfrag pa = *(const bfrag*)&W[row * 64 + (((kk * 4 + klo) ^ fs) << 3)];
#pragma unroll
          for (int nf = 0; nf < 4; ++nf)
            o[m2][nf] = mfma16x16x32(pa, vb[nf][kk], o[m2][nf]);
        }
      }
      // o -> W then coalesced uint4 stores
#pragma unroll
      for (int m2 = 0; m2 < 4; ++m2)
#pragma unroll
        for (int r = 0; r < 4; ++r) {
          const int row = m2 * 16 + klo * 4 + r;
          const int fs = fsw(row);
#pragma unroll
          for (int n = 0; n < 4; ++n) {
            const int cc = n * 16 + frow;
            W[row * 64 + ((((cc >> 3) ^ fs) << 3) | (cc & 7))] = f2bf(o[m2][n][r]);
          }
        }
      const size_t grow0 = arow0 + wm * 128 + hh * 64;
#pragma unroll
      for (int it = 0; it < 8; ++it) {
        const int idx = it * 64 + lane;
        const int rr = idx >> 3, gs = idx & 7;
        const int gcol = (gs ^ fsw(rr)) << 3;
        *(uint4*)&out1[(grow0 + rr) * 1024 + head * 64 + gcol] =
            *(const uint4*)&W[rr * 64 + gs * 8];
      }
    }
  }
}

// -------------------------------- launch --------------------------------
extern "C" void kernel_launch(void* const* d_in, const int* in_sizes, int n_in,
                              void* d_out, int out_size, void* d_ws, size_t ws_size,
                              hipStream_t stream) {
  const float* x = (const float*)d_in[0];
  const float* lat = (const float*)d_in[1];
  const float* lxg = (const float*)d_in[2];
  const float* lxb = (const float*)d_in[3];
  const float* llg = (const float*)d_in[4];
  const float* llb = (const float*)d_in[5];
  const float* Wq = (const float*)d_in[6];
  const float* Wkv = (const float*)d_in[7];
  const float* Wout = (const float*)d_in[8];
  float* out = (float*)d_out;
  char* ws = (char*)d_ws;

  // ws layout (142MB): xn 2MB | wqT 2MB | wkvT 4MB | woT 2MB | k 2MB | v 2MB | out1 128MB
  ushort_t* xn = (ushort_t*)(ws);
  ushort_t* wqT = (ushort_t*)(ws + (2ull << 20));
  ushort_t* wkvT = (ushort_t*)(ws + (4ull << 20));
  ushort_t* woT = (ushort_t*)(ws + (8ull << 20));
  ushort_t* kbuf = (ushort_t*)(ws + (10ull << 20));
  ushort_t* vbuf = (ushort_t*)(ws + (12ull << 20));
  ushort_t* out1 = (ushort_t*)(ws + (14ull << 20));
  // lnl (bf16, 128MB) lives in d_out's first half: dead before final GEMM writes d_out
  ushort_t* lnl = (ushort_t*)d_out;

  dim3 tb(32, 8);
  transpose_cast_kernel<<<dim3(1024 / 32, 32), tb, 0, stream>>>(Wq, wqT, 1024, 0.125f);
  transpose_cast_kernel<<<dim3(2048 / 32, 32), tb, 0, stream>>>(Wkv, wkvT, 2048, 1.0f);
  transpose_cast_kernel<<<dim3(1024 / 32, 32), tb, 0, stream>>>(Wout, woT, 1024, 1.0f);
  ln_rows_kernel<<<B_ * S_, 256, 0, stream>>>(x, lxg, lxb, xn);
  ln_rows_kernel<<<B_ * M_, 256, 0, stream>>>(lat, llg, llb, lnl);
  gemm_kv_kernel<<<dim3(8, 16), 256, 0, stream>>>(xn, wkvT, kbuf, vbuf);
  gemm256_kernel<1><<<1024, 512, 0, stream>>>(lnl, wqT, kbuf, vbuf, out1);
  gemm256_kernel<0><<<1024, 512, 0, stream>>>(out1, woT, nullptr, nullptr, out);
}

// Round 6
// 465.447 us; speedup vs baseline: 1.4411x; 1.0156x over previous
//
#include <hip/hip_runtime.h>
#include <stdint.h>

#define B_ 16
#define S_ 64
#define M_ 4096
#define D_ 1024
#define H_ 16
#define DH_ 64

typedef unsigned short ushort_t;
typedef __attribute__((ext_vector_type(8))) __bf16 bfrag;   // 8 bf16 = 4 VGPRs
typedef __attribute__((ext_vector_type(4))) float f32x4;

// fp32 -> bf16 RNE
__device__ __forceinline__ ushort_t f2bf(float f) {
  union { float f; uint32_t u; } v; v.f = f;
  uint32_t r = v.u + 0x7fffu + ((v.u >> 16) & 1u);
  return (ushort_t)(r >> 16);
}

__device__ __forceinline__ void gload_lds16(const void* g, void* l) {
  __builtin_amdgcn_global_load_lds((const __attribute__((address_space(1))) void*)g,
                                   (__attribute__((address_space(3))) void*)l, 16, 0, 0);
}

__device__ __forceinline__ f32x4 mfma16x16x32(bfrag a, bfrag b, f32x4 c) {
  return __builtin_amdgcn_mfma_f32_16x16x32_bf16(a, b, c, 0, 0, 0);
}

// epilogue-region swizzle: granule ^= fsw(row); fsw>>1 injective over klo groups
__device__ __forceinline__ int fsw(int r) { return (((r >> 2) & 3) << 1) | (r & 1); }

// ---------------- LayerNorm rows (1024 wide) -> bf16 ----------------
__global__ __launch_bounds__(256) void ln_rows_kernel(
    const float* __restrict__ x, const float* __restrict__ g,
    const float* __restrict__ bta, ushort_t* __restrict__ out) {
  const int row = blockIdx.x;
  const int t = threadIdx.x;
  const float4* xr = (const float4*)(x + (size_t)row * D_);
  float4 v = xr[t];
  float s = v.x + v.y + v.z + v.w;
  float ss = v.x * v.x + v.y * v.y + v.z * v.z + v.w * v.w;
#pragma unroll
  for (int o = 32; o >= 1; o >>= 1) { s += __shfl_down(s, o); ss += __shfl_down(ss, o); }
  __shared__ float red[16];
  const int wid = t >> 6;
  if ((t & 63) == 0) { red[wid] = s; red[8 + wid] = ss; }
  __syncthreads();
  float tot = red[0] + red[1] + red[2] + red[3];
  float tot2 = red[8] + red[9] + red[10] + red[11];
  float mu = tot * (1.0f / D_);
  float var = tot2 * (1.0f / D_) - mu * mu;
  float rstd = rsqrtf(var + 1e-5f);
  float4 gg = ((const float4*)g)[t];
  float4 bb = ((const float4*)bta)[t];
  ushort_t ob[4];
  ob[0] = f2bf((v.x - mu) * rstd * gg.x + bb.x);
  ob[1] = f2bf((v.y - mu) * rstd * gg.y + bb.y);
  ob[2] = f2bf((v.z - mu) * rstd * gg.z + bb.z);
  ob[3] = f2bf((v.w - mu) * rstd * gg.w + bb.w);
  *(uint2*)(out + (size_t)row * D_ + t * 4) = *(const uint2*)ob;
}

// ---------------- W[K=1024][N] fp32 -> WT[N][1024] bf16 (scaled) ----------------
__global__ void transpose_cast_kernel(const float* __restrict__ W, ushort_t* __restrict__ WT,
                                      int N, float scale) {
  __shared__ float tile[32][33];
  const int n0 = blockIdx.x * 32, k0 = blockIdx.y * 32;
  const int tx = threadIdx.x, ty = threadIdx.y;
#pragma unroll
  for (int i = ty; i < 32; i += 8)
    tile[i][tx] = W[(size_t)(k0 + i) * N + n0 + tx];
  __syncthreads();
#pragma unroll
  for (int i = ty; i < 32; i += 8)
    WT[(size_t)(n0 + i) * D_ + k0 + tx] = f2bf(tile[tx][i] * scale);
}

// ---------------- kv GEMM (small, 4.3 GF): 128x128, scatter to (b,h,s,d) ----------
__global__ __launch_bounds__(256) void gemm_kv_kernel(
    const ushort_t* __restrict__ A, const ushort_t* __restrict__ Bt,
    ushort_t* __restrict__ kb, ushort_t* __restrict__ vb) {
  __shared__ __align__(16) ushort_t sA[128 * 32];
  __shared__ __align__(16) ushort_t sB[128 * 32];
  const int tid = threadIdx.x, wid = tid >> 6, lane = tid & 63;
  const size_t arow0 = (size_t)blockIdx.x * 128;
  const size_t brow0 = (size_t)blockIdx.y * 128;
  const int wr = (wid >> 1) * 64, wc = (wid & 1) * 64;
  const int srow = tid >> 2, scol = (tid & 3) * 8;
  const ushort_t* ga = A + (arow0 + srow) * (size_t)D_ + scol;
  const ushort_t* gb = Bt + (brow0 + srow) * (size_t)D_ + scol;
  const int frow = lane & 15, kslot = (lane >> 4) * 8;
  f32x4 acc[4][4] = {};
  for (int k0 = 0; k0 < D_; k0 += 32) {
    gload_lds16(ga, sA + wid * 512);
    gload_lds16(ga + 64 * (size_t)D_, sA + 2048 + wid * 512);
    gload_lds16(gb, sB + wid * 512);
    gload_lds16(gb + 64 * (size_t)D_, sB + 2048 + wid * 512);
    ga += 32; gb += 32;
    __syncthreads();
    bfrag af[4], bfv[4];
#pragma unroll
    for (int m = 0; m < 4; ++m)
      af[m] = *(const bfrag*)&sA[(wr + m * 16 + frow) * 32 + kslot];
#pragma unroll
    for (int n = 0; n < 4; ++n)
      bfv[n] = *(const bfrag*)&sB[(wc + n * 16 + frow) * 32 + kslot];
#pragma unroll
    for (int m = 0; m < 4; ++m)
#pragma unroll
      for (int n = 0; n < 4; ++n)
        acc[m][n] = mfma16x16x32(af[m], bfv[n], acc[m][n]);
    __syncthreads();
  }
  const int erow = (lane >> 4) * 4, ecol = lane & 15;
#pragma unroll
  for (int m = 0; m < 4; ++m)
#pragma unroll
    for (int n = 0; n < 4; ++n)
#pragma unroll
      for (int r = 0; r < 4; ++r) {
        size_t i = arow0 + wr + m * 16 + erow + r;
        int bb = (int)(i >> 6), s = (int)(i & 63);
        size_t n2 = brow0 + wc + n * 16 + ecol;
        ushort_t val = f2bf(acc[m][n][r]);
        ushort_t* dst = (n2 < 1024) ? kb : vb;
        size_t hh = (n2 & 1023) >> 6, d = n2 & 63;
        dst[(((size_t)bb * H_ + hh) * S_ + s) * DH_ + d] = val;
      }
}

// ============== 256x256 read-ahead-pipelined GEMM, C = A * Bt^T ====================
// ghalf g = K cols [g*32, g*32+32), 16KB slot; 4-slot ring/operand (128KB LDS).
// 8 waves (2m x 4n), per-wave 128x64 out. 2 phases per ghalf, ONE barrier each.
// REGISTER READ-AHEAD: phase p's MFMA consumes frags ds_read during phase p-1
// (reads interleaved inside the MFMA cluster), so post-barrier lgkmcnt(0) drains
// reads issued a full phase (~800cyc) earlier -> no LDS stall on critical path.
// vmcnt(6) once per ghalf (exact: prologue 12 loads + 2/phase; B(g+1) staged 4
// phases back => allowed outstanding = 6). Stage lead = 3 ghalfs, slot reuse is
// >=2 barriers after last read (ring distance) -> trailing barrier removed.
// MODE 0: epilogue = fp32 C store; MODE 1: fused attention per wave-half.
template <int MODE>
__global__ __launch_bounds__(512, 2) void gemm256_kernel(
    const ushort_t* __restrict__ A, const ushort_t* __restrict__ Bt,
    const ushort_t* __restrict__ kbuf, const ushort_t* __restrict__ vbuf,
    void* __restrict__ Cout) {
  __shared__ __align__(16) ushort_t lds[65536];  // 128KB: A ring 64KB | B ring 64KB
  const int tid = threadIdx.x, wid = tid >> 6, lane = tid & 63;
  const int frow = lane & 15, klo = lane >> 4;
  const int wm = wid >> 2, wn = wid & 3;

  // XCD-swizzled block mapping (1024 = 8*128, bijective)
  const int l = ((int)blockIdx.x & 7) * 128 + ((int)blockIdx.x >> 3);
  const int mblk = l >> 2, nblk = l & 3;
  const size_t arow0 = (size_t)mblk * 256;
  const size_t bcol0 = (size_t)nblk * 256;

  // ---- staging constants: thread covers (row, gidx) = (tid>>2, tid&3)
  // stored granule gidx holds source granule gidx ^ ((row>>1)&3)
  const int r0 = tid >> 2;
  const int gsrc = (tid & 3) ^ ((tid >> 3) & 3);
  const ushort_t* pA0 = A + (arow0 + r0) * (size_t)D_ + gsrc * 8;
  const ushort_t* pA1 = pA0 + (size_t)128 * D_;
  const ushort_t* pB0 = Bt + (bcol0 + r0) * (size_t)D_ + gsrc * 8;
  const ushort_t* pB1 = pB0 + (size_t)128 * D_;
  // ds_read swizzled granule offset (constant per lane)
  const int rasw = (klo ^ ((frow >> 1) & 3)) * 8;

#define STAGE_A(G)                                                            \
  do {                                                                        \
    const int s_ = (G) & 3;                                                   \
    const size_t ko_ = (size_t)((G) < 32 ? (G) : 31) * 32;                    \
    gload_lds16(pA0 + ko_, &lds[s_ * 8192 + wid * 512]);                      \
    gload_lds16(pA1 + ko_, &lds[s_ * 8192 + 4096 + wid * 512]);               \
  } while (0)
#define STAGE_B(G)                                                            \
  do {                                                                        \
    const int s_ = (G) & 3;                                                   \
    const size_t ko_ = (size_t)((G) < 32 ? (G) : 31) * 32;                    \
    gload_lds16(pB0 + ko_, &lds[32768 + s_ * 8192 + wid * 512]);              \
    gload_lds16(pB1 + ko_, &lds[32768 + s_ * 8192 + 4096 + wid * 512]);       \
  } while (0)

  // prologue: ghalfs 0,1,2 staged; first 4 loads (A0,B0) verified; read phase-0 frags
  STAGE_A(0); STAGE_B(0);
  STAGE_A(1); STAGE_B(1);
  STAGE_A(2); STAGE_B(2);
  asm volatile("s_waitcnt vmcnt(8)" ::: "memory");
  __builtin_amdgcn_s_barrier();
  bfrag aC[4], aN[4], bC[4], bN[4];
  {
    const ushort_t* As = &lds[0];
    const ushort_t* Bs = &lds[32768];
#pragma unroll
    for (int mf = 0; mf < 4; ++mf)
      aC[mf] = *(const bfrag*)&As[(wm * 128 + mf * 16 + frow) * 32 + rasw];
#pragma unroll
    for (int nf = 0; nf < 4; ++nf)
      bC[nf] = *(const bfrag*)&Bs[(wn * 64 + nf * 16 + frow) * 32 + rasw];
  }

  f32x4 acc[8][4] = {};
  for (int g = 0; g < 32; ++g) {
    // ---------------- phase 0 (mh=0): MFMA(aC,bC); read-ahead aN = A(g,mh1) -------
    __builtin_amdgcn_s_barrier();
    asm volatile("s_waitcnt lgkmcnt(0)" ::: "memory");
    __builtin_amdgcn_sched_barrier(0);
    __builtin_amdgcn_s_setprio(1);
    {
      const ushort_t* As = &lds[(g & 3) * 8192];
#pragma unroll
      for (int mf = 0; mf < 4; ++mf) {
#pragma unroll
        for (int nf = 0; nf < 4; ++nf)
          acc[mf][nf] = mfma16x16x32(aC[mf], bC[nf], acc[mf][nf]);
        aN[mf] = *(const bfrag*)&As[(wm * 128 + 64 + mf * 16 + frow) * 32 + rasw];
      }
    }
    __builtin_amdgcn_s_setprio(0);
    STAGE_A(g + 3);
    // ---------------- phase 1 (mh=1): MFMA(aN,bC); read-ahead aC,bN = {A,B}(g+1) --
    asm volatile("s_waitcnt vmcnt(6)" ::: "memory");
    __builtin_amdgcn_s_barrier();
    asm volatile("s_waitcnt lgkmcnt(0)" ::: "memory");
    __builtin_amdgcn_sched_barrier(0);
    __builtin_amdgcn_s_setprio(1);
    {
      const int gn = (g + 1 < 32) ? g + 1 : 31;
      const ushort_t* As2 = &lds[(gn & 3) * 8192];
      const ushort_t* Bs2 = &lds[32768 + (gn & 3) * 8192];
#pragma unroll
      for (int mf = 0; mf < 4; ++mf) {
#pragma unroll
        for (int nf = 0; nf < 4; ++nf)
          acc[4 + mf][nf] = mfma16x16x32(aN[mf], bC[nf], acc[4 + mf][nf]);
        aC[mf] = *(const bfrag*)&As2[(wm * 128 + mf * 16 + frow) * 32 + rasw];
        bN[mf] = *(const bfrag*)&Bs2[(wn * 64 + mf * 16 + frow) * 32 + rasw];
      }
    }
    __builtin_amdgcn_s_setprio(0);
    STAGE_B(g + 3);
#pragma unroll
    for (int nf = 0; nf < 4; ++nf) bC[nf] = bN[nf];
  }
  // drain tail stages before reusing LDS / exiting
  asm volatile("s_waitcnt vmcnt(0)" ::: "memory");
  __builtin_amdgcn_s_barrier();
  __builtin_amdgcn_sched_barrier(0);
#undef STAGE_A
#undef STAGE_B

  if constexpr (MODE == 0) {
    // ---------------- epilogue: fp32 C store (acc[m] rows = m*16 + klo*4 + r) -----
    float* C = (float*)Cout;
#pragma unroll
    for (int m = 0; m < 8; ++m)
#pragma unroll
      for (int n = 0; n < 4; ++n)
#pragma unroll
        for (int r = 0; r < 4; ++r)
          C[(arow0 + wm * 128 + m * 16 + klo * 4 + r) * 1024 + bcol0 + wn * 64 + n * 16 + frow] =
              acc[m][n][r];
  } else {
    // ---------------- epilogue: fused attention (wave-private) ----------------
    ushort_t* W = &lds[wid * 4096];  // [64][64] bf16, granule ^= fsw(row)
    ushort_t* out1 = (ushort_t*)Cout;
    const int head = nblk * 4 + wn;
    const int bbatch = mblk >> 4;
    const size_t kvbase = ((size_t)bbatch * H_ + head) * (size_t)(S_ * DH_);
    bfrag kb[4][2], vb[4][2];
#pragma unroll
    for (int nf = 0; nf < 4; ++nf)
#pragma unroll
      for (int kk = 0; kk < 2; ++kk) {
        kb[nf][kk] = *(const bfrag*)&kbuf[kvbase + (nf * 16 + frow) * 64 + kk * 32 + klo * 8];
        vb[nf][kk] = *(const bfrag*)&vbuf[kvbase + (nf * 16 + frow) * 64 + kk * 32 + klo * 8];
      }
#pragma unroll
    for (int hh = 0; hh < 2; ++hh) {
      // q -> W (bf16, swizzled)
#pragma unroll
      for (int m2 = 0; m2 < 4; ++m2)
#pragma unroll
        for (int r = 0; r < 4; ++r) {
          const int row = m2 * 16 + klo * 4 + r;
          const int fs = fsw(row);
#pragma unroll
          for (int n = 0; n < 4; ++n) {
            const int cc = n * 16 + frow;
            W[row * 64 + ((((cc >> 3) ^ fs) << 3) | (cc & 7))] = f2bf(acc[hh * 4 + m2][n][r]);
          }
        }
      // sim = q @ K^T
      f32x4 s[4][4] = {};
#pragma unroll
      for (int m2 = 0; m2 < 4; ++m2) {
        const int row = m2 * 16 + frow;
        const int fs = fsw(row);
#pragma unroll
        for (int kk = 0; kk < 2; ++kk) {
          bfrag qa = *(const bfrag*)&W[row * 64 + (((kk * 4 + klo) ^ fs) << 3)];
#pragma unroll
          for (int nf = 0; nf < 4; ++nf)
            s[m2][nf] = mfma16x16x32(qa, kb[nf][kk], s[m2][nf]);
        }
      }
      // softmax over 64 keys (row in one 16-lane group, 4 keys/lane/frag)
#pragma unroll
      for (int m2 = 0; m2 < 4; ++m2)
#pragma unroll
        for (int r = 0; r < 4; ++r) {
          float a0 = s[m2][0][r], a1 = s[m2][1][r], a2 = s[m2][2][r], a3 = s[m2][3][r];
          float mx = fmaxf(fmaxf(a0, a1), fmaxf(a2, a3));
#pragma unroll
          for (int o = 1; o < 16; o <<= 1) mx = fmaxf(mx, __shfl_xor(mx, o));
          a0 = __expf(a0 - mx); a1 = __expf(a1 - mx);
          a2 = __expf(a2 - mx); a3 = __expf(a3 - mx);
          float sm = (a0 + a1) + (a2 + a3);
#pragma unroll
          for (int o = 1; o < 16; o <<= 1) sm += __shfl_xor(sm, o);
          const float inv = 1.0f / sm;
          s[m2][0][r] = a0 * inv; s[m2][1][r] = a1 * inv;
          s[m2][2][r] = a2 * inv; s[m2][3][r] = a3 * inv;
        }
      // P -> W (overwrite q; wave-private, in-order LDS)
#pragma unroll
      for (int m2 = 0; m2 < 4; ++m2)
#pragma unroll
        for (int r = 0; r < 4; ++r) {
          const int row = m2 * 16 + klo * 4 + r;
          const int fs = fsw(row);
#pragma unroll
          for (int n = 0; n < 4; ++n) {
            const int cc = n * 16 + frow;
            W[row * 64 + ((((cc >> 3) ^ fs) << 3) | (cc & 7))] = f2bf(s[m2][n][r]);
          }
        }
      // out1_half = attn @ "V^T" (einsum quirk: contract attn-keys with V dims)
      f32x4 o[4][4] = {};
#pragma unroll
      for (int m2 = 0; m2 < 4; ++m2) {
        const int row = m2 * 16 + frow;
        const int fs = fsw(row);
#pragma unroll
        for (int kk = 0; kk < 2; ++kk) {
          bfrag pa = *(const bfrag*)&W[row * 64 + (((kk * 4 + klo) ^ fs) << 3)];
#pragma unroll
          for (int nf = 0; nf < 4; ++nf)
            o[m2][nf] = mfma16x16x32(pa, vb[nf][kk], o[m2][nf]);
        }
      }
      // o -> W then coalesced uint4 stores
#pragma unroll
      for (int m2 = 0; m2 < 4; ++m2)
#pragma unroll
        for (int r = 0; r < 4; ++r) {
          const int row = m2 * 16 + klo * 4 + r;
          const int fs = fsw(row);
#pragma unroll
          for (int n = 0; n < 4; ++n) {
            const int cc = n * 16 + frow;
            W[row * 64 + ((((cc >> 3) ^ fs) << 3) | (cc & 7))] = f2bf(o[m2][n][r]);
          }
        }
      const size_t grow0 = arow0 + wm * 128 + hh * 64;
#pragma unroll
      for (int it = 0; it < 8; ++it) {
        const int idx = it * 64 + lane;
        const int rr = idx >> 3, gs = idx & 7;
        const int gcol = (gs ^ fsw(rr)) << 3;
        *(uint4*)&out1[(grow0 + rr) * 1024 + head * 64 + gcol] =
            *(const uint4*)&W[rr * 64 + gs * 8];
      }
    }
  }
}

// -------------------------------- launch --------------------------------
extern "C" void kernel_launch(void* const* d_in, const int* in_sizes, int n_in,
                              void* d_out, int out_size, void* d_ws, size_t ws_size,
                              hipStream_t stream) {
  const float* x = (const float*)d_in[0];
  const float* lat = (const float*)d_in[1];
  const float* lxg = (const float*)d_in[2];
  const float* lxb = (const float*)d_in[3];
  const float* llg = (const float*)d_in[4];
  const float* llb = (const float*)d_in[5];
  const float* Wq = (const float*)d_in[6];
  const float* Wkv = (const float*)d_in[7];
  const float* Wout = (const float*)d_in[8];
  float* out = (float*)d_out;
  char* ws = (char*)d_ws;

  // ws layout (142MB): xn 2MB | wqT 2MB | wkvT 4MB | woT 2MB | k 2MB | v 2MB | out1 128MB
  ushort_t* xn = (ushort_t*)(ws);
  ushort_t* wqT = (ushort_t*)(ws + (2ull << 20));
  ushort_t* wkvT = (ushort_t*)(ws + (4ull << 20));
  ushort_t* woT = (ushort_t*)(ws + (8ull << 20));
  ushort_t* kbuf = (ushort_t*)(ws + (10ull << 20));
  ushort_t* vbuf = (ushort_t*)(ws + (12ull << 20));
  ushort_t* out1 = (ushort_t*)(ws + (14ull << 20));
  // lnl (bf16, 128MB) lives in d_out's first half: dead before final GEMM writes d_out
  ushort_t* lnl = (ushort_t*)d_out;

  dim3 tb(32, 8);
  transpose_cast_kernel<<<dim3(1024 / 32, 32), tb, 0, stream>>>(Wq, wqT, 1024, 0.125f);
  transpose_cast_kernel<<<dim3(2048 / 32, 32), tb, 0, stream>>>(Wkv, wkvT, 2048, 1.0f);
  transpose_cast_kernel<<<dim3(1024 / 32, 32), tb, 0, stream>>>(Wout, woT, 1024, 1.0f);
  ln_rows_kernel<<<B_ * S_, 256, 0, stream>>>(x, lxg, lxb, xn);
  ln_rows_kernel<<<B_ * M_, 256, 0, stream>>>(lat, llg, llb, lnl);
  gemm_kv_kernel<<<dim3(8, 16), 256, 0, stream>>>(xn, wkvT, kbuf, vbuf);
  gemm256_kernel<1><<<1024, 512, 0, stream>>>(lnl, wqT, kbuf, vbuf, out1);
  gemm256_kernel<0><<<1024, 512, 0, stream>>>(out1, woT, nullptr, nullptr, out);
}